// Round 4
// baseline (598.797 us; speedup 1.0000x reference)
//
#include <hip/hip_runtime.h>

typedef __bf16 bf16;
typedef __bf16 v8bf __attribute__((ext_vector_type(8)));
typedef float  v4f  __attribute__((ext_vector_type(4)));
typedef float  v16f __attribute__((ext_vector_type(16)));
typedef unsigned short u16;
typedef u16 v8us __attribute__((ext_vector_type(8)));
typedef unsigned int v4u __attribute__((ext_vector_type(4)));

#define L_ 4
#define B_ 32
#define N_ 512
#define D_ 256
#define H_ 8
#define F_ 1024
#define ROWS (B_*N_)   // 16384

__device__ __forceinline__ void gload16(const void* g, void* l) {
  __builtin_amdgcn_global_load_lds((__attribute__((address_space(1))) void*)g,
                                   (__attribute__((address_space(3))) void*)l,
                                   16, 0, 0);
}

__device__ __forceinline__ unsigned pk_bf16(float a, float b) {
  unsigned r;
  asm("v_cvt_pk_bf16_f32 %0, %1, %2" : "=v"(r) : "v"(a), "v"(b));
  return r;
}

#define EXP2(x) __builtin_amdgcn_exp2f(x)

// ---------------- biasP (permuted, MFMA C-layout) = (e2 @ e1^T) * log2e ----------------
// biasP float4 layout: [blk = kb*8 + g*2 + hi][q=512] of float4 over j
// where k-row = kb*32 + 8g + 4hi + j
__global__ __launch_bounds__(256) void bias_gemm(
    const float* __restrict__ e1, const float* __restrict__ e2,
    float* __restrict__ biasP) {
  __shared__ float As[16][16];
  __shared__ float Bs[16][16];
  const int tx = threadIdx.x, ty = threadIdx.y;
  const int r = blockIdx.y * 16 + ty, c = blockIdx.x * 16 + tx;
  float acc = 0.f;
  for (int k0 = 0; k0 < D_; k0 += 16) {
    As[ty][tx] = e1[r * D_ + k0 + tx];
    Bs[ty][tx] = e2[(blockIdx.x * 16 + ty) * D_ + k0 + tx];
    __syncthreads();
#pragma unroll
    for (int kk = 0; kk < 16; ++kk) acc += As[ty][kk] * Bs[tx][kk];
    __syncthreads();
  }
  const int kb = r >> 5, r5 = r & 31;
  const int blk = kb * 8 + (r5 >> 3) * 2 + ((r5 >> 2) & 1);
  biasP[(size_t)(blk * 512 + c) * 4 + (r5 & 3)] = acc * 1.4426950408889634f;
}

// ---------------- mq[q] = max over all k of biasP ----------------
__global__ __launch_bounds__(256) void colmax(
    const float* __restrict__ biasP, float* __restrict__ mq) {
  const int q = blockIdx.x * 256 + threadIdx.x;
  float mx = -1e30f;
  for (int blk = 0; blk < 128; ++blk) {
    const float4 v = *(const float4*)&biasP[(size_t)(blk * 512 + q) * 4];
    mx = fmaxf(mx, fmaxf(fmaxf(v.x, v.y), fmaxf(v.z, v.w)));
  }
  mq[q] = mx;
}

// ---------------- biasP -= mq[q] ----------------
__global__ __launch_bounds__(256) void subm(
    float* __restrict__ biasP, const float* __restrict__ mq) {
  const int i = blockIdx.x * 256 + threadIdx.x;  // 65536 float4
  float4 v = ((float4*)biasP)[i];
  const float m = mq[i & 511];
  v.x -= m; v.y -= m; v.z -= m; v.w -= m;
  ((float4*)biasP)[i] = v;
}

// ---------------- tiled weight transpose + bf16 cast: [K][N] -> [N][K] ----------------
__global__ __launch_bounds__(256) void convT(
    const float* __restrict__ W, bf16* __restrict__ Wt,
    int K, int N, size_t inL, size_t outL) {
  __shared__ float t[32][33];
  const int l = blockIdx.z;
  const int k0 = blockIdx.y * 32, n0 = blockIdx.x * 32;
  const int r = threadIdx.x >> 5, c = threadIdx.x & 31;
#pragma unroll
  for (int i = 0; i < 4; ++i)
    t[r + 8 * i][c] = W[l * inL + (size_t)(k0 + r + 8 * i) * N + n0 + c];
  __syncthreads();
#pragma unroll
  for (int i = 0; i < 4; ++i)
    Wt[l * outL + (size_t)(n0 + r + 8 * i) * K + k0 + c] = (bf16)t[c][r + 8 * i];
}

__global__ __launch_bounds__(256) void pack_bqkv(
    const float* __restrict__ bq, const float* __restrict__ bk,
    const float* __restrict__ bv, float* __restrict__ bqkv) {
  const int i = blockIdx.x * 256 + threadIdx.x;
  if (i < L_ * 768) {
    const int l = i / 768, n = i - l * 768;
    float v = (n < 256) ? bq[l * 256 + n]
            : (n < 512) ? bk[l * 256 + n - 256]
                        : bv[l * 256 + n - 512];
    bqkv[i] = v;
  }
}

__global__ __launch_bounds__(256) void init_x(
    const float* __restrict__ src, float* __restrict__ x,
    bf16* __restrict__ xb) {
  const int i = blockIdx.x * 256 + threadIdx.x;  // float4 index
  float4 v = ((const float4*)src)[i];
  ((float4*)x)[i] = v;
  uint2 w;
  w.x = pk_bf16(v.x, v.y);
  w.y = pk_bf16(v.z, v.w);
  ((uint2*)xb)[i] = w;
}

// ---------------- bf16 MFMA GEMM: C[M][N] = A[M][K] @ Bt[N][K]^T + bias ----------------
template <int BM, int RELU, int OUTBF16>
__global__ __launch_bounds__(256, 2) void gemm_bf16k(
    const bf16* __restrict__ A, const bf16* __restrict__ Bt,
    const float* __restrict__ bias, void* __restrict__ Cout,
    int M, int N, int K) {
  constexpr int MR = BM / 32;
  constexpr int NSLAB = BM / 16 + 8;
  __shared__ __align__(16) bf16 As[BM * 32];
  __shared__ __align__(16) bf16 Bs[128 * 32];
  const int tid  = threadIdx.x;
  const int wave = tid >> 6, lane = tid & 63;
  const int l15 = lane & 15, l4 = lane >> 4;
  const int bm = blockIdx.y * BM, bn = blockIdx.x * 128;
  const int wr = (wave >> 1) * (BM / 2), wc = (wave & 1) * 64;
  const int lrow = lane >> 2;
  const int lk   = (lane & 3) * 8;

  v4f acc[MR][4];
#pragma unroll
  for (int m = 0; m < MR; ++m)
#pragma unroll
    for (int n = 0; n < 4; ++n) acc[m][n] = (v4f){0.f, 0.f, 0.f, 0.f};

  for (int k0 = 0; k0 < K; k0 += 32) {
#pragma unroll
    for (int s = wave; s < NSLAB; s += 4) {
      if (s < BM / 16)
        gload16(A + (size_t)(bm + s * 16 + lrow) * K + k0 + lk, &As[s * 16 * 32]);
      else {
        const int sb = s - BM / 16;
        gload16(Bt + (size_t)(bn + sb * 16 + lrow) * K + k0 + lk, &Bs[sb * 16 * 32]);
      }
    }
    __syncthreads();
    v8bf af[MR], bfr[4];
#pragma unroll
    for (int m = 0; m < MR; ++m)
      af[m] = *(const v8bf*)&As[(wr + m * 16 + l15) * 32 + l4 * 8];
#pragma unroll
    for (int n = 0; n < 4; ++n)
      bfr[n] = *(const v8bf*)&Bs[(wc + n * 16 + l15) * 32 + l4 * 8];
#pragma unroll
    for (int m = 0; m < MR; ++m)
#pragma unroll
      for (int n = 0; n < 4; ++n)
        acc[m][n] = __builtin_amdgcn_mfma_f32_16x16x32_bf16(af[m], bfr[n], acc[m][n], 0, 0, 0);
    __syncthreads();
  }

#pragma unroll
  for (int m = 0; m < MR; ++m) {
    const int row0 = bm + wr + m * 16 + l4 * 4;
#pragma unroll
    for (int n = 0; n < 4; ++n) {
      const int col = bn + wc + n * 16 + l15;
      const float bc = bias[col];
#pragma unroll
      for (int i = 0; i < 4; ++i) {
        float v = acc[m][n][i] + bc;
        if (RELU) v = fmaxf(v, 0.f);
        const size_t idx = (size_t)(row0 + i) * N + col;
        if (OUTBF16) ((bf16*)Cout)[idx] = (bf16)v;
        else         ((float*)Cout)[idx] = v;
      }
    }
  }
}

// ---------------- fused GEMM (N=256) + residual + LayerNorm ----------------
// y = LN(A@Bt^T + bias + xres); writes xout fp32, xbout bf16. 512 threads, BM=64.
__global__ __launch_bounds__(512, 1) void gemm_ln(
    const bf16* __restrict__ A, const bf16* __restrict__ Bt,
    const float* __restrict__ bias, const float* __restrict__ xres,
    const float* __restrict__ g, const float* __restrict__ be,
    float* __restrict__ xout, bf16* __restrict__ xbout, int K) {
  __shared__ __align__(16) bf16 As[64 * 32];
  __shared__ __align__(16) bf16 Bs[256 * 32];
  __shared__ float redS[2][64], redSS[2][64];
  const int tid = threadIdx.x, wave = tid >> 6, lane = tid & 63;
  const int l15 = lane & 15, l4 = lane >> 4;
  const int w4 = wave & 3, half = wave >> 2;
  const int bm = blockIdx.x * 64;
  const int lrow = lane >> 2, lk = (lane & 3) * 8;

  v4f acc[8];
#pragma unroll
  for (int n = 0; n < 8; ++n) acc[n] = (v4f){0.f, 0.f, 0.f, 0.f};

  for (int k0 = 0; k0 < K; k0 += 32) {
#pragma unroll
    for (int s = wave; s < 20; s += 8) {
      if (s < 4)
        gload16(A + (size_t)(bm + s * 16 + lrow) * K + k0 + lk, &As[s * 512]);
      else
        gload16(Bt + (size_t)((s - 4) * 16 + lrow) * K + k0 + lk, &Bs[(s - 4) * 512]);
    }
    __syncthreads();
    const v8bf af = *(const v8bf*)&As[(w4 * 16 + l15) * 32 + l4 * 8];
#pragma unroll
    for (int n = 0; n < 8; ++n) {
      const v8bf bfr = *(const v8bf*)&Bs[((half * 8 + n) * 16 + l15) * 32 + l4 * 8];
      acc[n] = __builtin_amdgcn_mfma_f32_16x16x32_bf16(af, bfr, acc[n], 0, 0, 0);
    }
    __syncthreads();
  }

  // epilogue: +bias +residual, LN over row
  const int row0 = bm + w4 * 16 + l4 * 4;
  const int colb = half * 128 + l15;
  float s[4] = {0.f, 0.f, 0.f, 0.f}, ss[4] = {0.f, 0.f, 0.f, 0.f};
  float bcol[8];
#pragma unroll
  for (int n = 0; n < 8; ++n) bcol[n] = bias[colb + n * 16];
#pragma unroll
  for (int n = 0; n < 8; ++n)
#pragma unroll
    for (int i = 0; i < 4; ++i) {
      float v = acc[n][i] + bcol[n] + xres[(size_t)(row0 + i) * 256 + colb + n * 16];
      acc[n][i] = v;
      s[i] += v; ss[i] += v * v;
    }
#pragma unroll
  for (int off = 1; off < 16; off <<= 1)
#pragma unroll
    for (int i = 0; i < 4; ++i) {
      s[i]  += __shfl_xor(s[i], off);
      ss[i] += __shfl_xor(ss[i], off);
    }
  if (l15 == 0) {
#pragma unroll
    for (int i = 0; i < 4; ++i) {
      redS[half][w4 * 16 + l4 * 4 + i]  = s[i];
      redSS[half][w4 * 16 + l4 * 4 + i] = ss[i];
    }
  }
  __syncthreads();
  float mu[4], rs[4];
#pragma unroll
  for (int i = 0; i < 4; ++i) {
    const int ri = w4 * 16 + l4 * 4 + i;
    const float S  = redS[0][ri] + redS[1][ri];
    const float SS = redSS[0][ri] + redSS[1][ri];
    mu[i] = S * (1.f / 256.f);
    const float var = SS * (1.f / 256.f) - mu[i] * mu[i];
    rs[i] = rsqrtf(var + 1e-5f);
  }
  float gcol[8], becol[8];
#pragma unroll
  for (int n = 0; n < 8; ++n) {
    gcol[n]  = g[colb + n * 16];
    becol[n] = be[colb + n * 16];
  }
#pragma unroll
  for (int n = 0; n < 8; ++n)
#pragma unroll
    for (int i = 0; i < 4; ++i) {
      const float o = (acc[n][i] - mu[i]) * rs[i] * gcol[n] + becol[n];
      const size_t idx = (size_t)(row0 + i) * 256 + colb + n * 16;
      xout[idx] = o;
      xbout[idx] = (bf16)o;
    }
}

// ---------------- fused flash attention, swapped-operand 32x32, fixed normalizer ----------------
// qkv: [B*N][768] bf16; biasP: permuted C-layout table (pre-max-subtracted, *log2e)
#define VTS 520
__global__ __launch_bounds__(256, 4) void attn_k(
    const bf16* __restrict__ qkv, const float* __restrict__ biasP,
    bf16* __restrict__ outp) {
  __shared__ u16 Vt[32 * VTS];   // V^T: [d][kc]
  const int tid = threadIdx.x;
  const int wave = tid >> 6, lane = tid & 63;
  const int l31 = lane & 31, hi = lane >> 5;
  const int bh = blockIdx.y, b = bh >> 3, h = bh & 7;
  const u16* base = (const u16*)qkv + (size_t)b * N_ * 768;
  const int qb = blockIdx.x * 128 + wave * 32;

  // ---- stage V^T (once per block): thread t packs rows 2t,2t+1 ----
  {
    const u16* vb = base + 512 + h * 32;
    const u16* p0 = vb + (size_t)(2 * tid) * 768;
    const u16* p1 = p0 + 768;
#pragma unroll
    for (int d0 = 0; d0 < 32; d0 += 8) {
      v8us a = *(const v8us*)(p0 + d0);
      v8us c = *(const v8us*)(p1 + d0);
#pragma unroll
      for (int j = 0; j < 8; ++j) {
        unsigned u = (unsigned)a[j] | ((unsigned)c[j] << 16);
        *(unsigned*)&Vt[(d0 + j) * VTS + tid * 2] = u;
      }
    }
  }
  __syncthreads();

  // ---- Q fragments (B operand), held all chunks ----
  const u16* qrow = base + (size_t)(qb + l31) * 768 + h * 32;
  const v8bf qf0 = *(const v8bf*)(qrow + hi * 8);
  const v8bf qf1 = *(const v8bf*)(qrow + 16 + hi * 8);
  const u16* kvb = base + 256 + h * 32;
  const float* bpl = biasP + ((size_t)(hi * 512 + qb + l31)) * 4;

  const float SC2 = 0.17677669529663688f * 1.4426950408889634f;
  float lsum = 0.f;
  v16f accO = {0.f,0.f,0.f,0.f,0.f,0.f,0.f,0.f,0.f,0.f,0.f,0.f,0.f,0.f,0.f,0.f};

  // prefetch chunk 0
  v8bf ka0 = *(const v8bf*)(kvb + (size_t)l31 * 768 + hi * 8);
  v8bf ka1 = *(const v8bf*)(kvb + (size_t)l31 * 768 + 16 + hi * 8);
  v4f bb[4];
#pragma unroll
  for (int g = 0; g < 4; ++g) bb[g] = *(const v4f*)(bpl + (size_t)(g * 2) * 2048);

  for (int kb = 0; kb < 16; ++kb) {
    const int kbase = kb * 32;
    v16f st = {0.f,0.f,0.f,0.f,0.f,0.f,0.f,0.f,0.f,0.f,0.f,0.f,0.f,0.f,0.f,0.f};
    st = __builtin_amdgcn_mfma_f32_32x32x16_bf16(ka0, qf0, st, 0, 0, 0);
    st = __builtin_amdgcn_mfma_f32_32x32x16_bf16(ka1, qf1, st, 0, 0, 0);

    // prefetch next chunk (unconditional; buffers padded)
    const u16* kn = kvb + (size_t)(kbase + 32 + l31) * 768;
    const v8bf kn0 = *(const v8bf*)(kn + hi * 8);
    const v8bf kn1 = *(const v8bf*)(kn + 16 + hi * 8);
    v4f bn[4];
#pragma unroll
    for (int g = 0; g < 4; ++g)
      bn[g] = *(const v4f*)(bpl + (size_t)((kb + 1) * 8 + g * 2) * 2048);

    // p = exp2(st*scale*log2e + biasP)
    float p[16];
#pragma unroll
    for (int r = 0; r < 16; ++r)
      p[r] = EXP2(st[r] * SC2 + bb[r >> 2][r & 3]);

    // lane-local partial sum
    float s8[8], s4[4];
#pragma unroll
    for (int r = 0; r < 8; ++r) s8[r] = p[r] + p[r + 8];
#pragma unroll
    for (int r = 0; r < 4; ++r) s4[r] = s8[r] + s8[r + 4];
    lsum += (s4[0] + s4[2]) + (s4[1] + s4[3]);

    // P -> bf16, redistribute into PV B-fragments
    unsigned u[8], x[8];
#pragma unroll
    for (int t = 0; t < 8; ++t) {
      u[t] = pk_bf16(p[2 * t], p[2 * t + 1]);
      x[t] = (unsigned)__shfl_xor((int)u[t], 32);
    }
    v4u b0 = (v4u){hi ? x[2] : u[0], hi ? x[3] : u[1], hi ? u[2] : x[0], hi ? u[3] : x[1]};
    v4u b1 = (v4u){hi ? x[6] : u[4], hi ? x[7] : u[5], hi ? u[6] : x[4], hi ? u[7] : x[5]};
    union { v4u u; v8bf h; } cv0, cv1;
    cv0.u = b0; cv1.u = b1;

    const v8bf va0 = *(const v8bf*)&Vt[l31 * VTS + kbase + hi * 8];
    const v8bf va1 = *(const v8bf*)&Vt[l31 * VTS + kbase + 16 + hi * 8];
    accO = __builtin_amdgcn_mfma_f32_32x32x16_bf16(va0, cv0.h, accO, 0, 0, 0);
    accO = __builtin_amdgcn_mfma_f32_32x32x16_bf16(va1, cv1.h, accO, 0, 0, 0);

    ka0 = kn0; ka1 = kn1;
#pragma unroll
    for (int g = 0; g < 4; ++g) bb[g] = bn[g];
  }

  lsum += __shfl_xor(lsum, 32);

  // ---- epilogue: O^T[d][q] regs -> out[q][h*32+d] ----
  const float inv = 1.0f / lsum;
  u16* orow = (u16*)outp + (size_t)(b * N_ + qb + l31) * D_ + h * 32 + 4 * hi;
#pragma unroll
  for (int g = 0; g < 4; ++g) {
    uint2 w;
    w.x = pk_bf16(accO[4 * g] * inv, accO[4 * g + 1] * inv);
    w.y = pk_bf16(accO[4 * g + 2] * inv, accO[4 * g + 3] * inv);
    *(uint2*)(orow + 8 * g) = w;
  }
}

extern "C" void kernel_launch(void* const* d_in, const int* in_sizes, int n_in,
                              void* d_out, int out_size, void* d_ws, size_t ws_size,
                              hipStream_t stream) {
  const float* src = (const float*)d_in[0];
  const float* e1  = (const float*)d_in[1];
  const float* e2  = (const float*)d_in[2];
  const float* Wq  = (const float*)d_in[3];
  const float* bq  = (const float*)d_in[4];
  const float* Wk  = (const float*)d_in[5];
  const float* bk  = (const float*)d_in[6];
  const float* Wv  = (const float*)d_in[7];
  const float* bv  = (const float*)d_in[8];
  const float* Wo  = (const float*)d_in[9];
  const float* bo  = (const float*)d_in[10];
  const float* W1  = (const float*)d_in[11];
  const float* b1  = (const float*)d_in[12];
  const float* W2  = (const float*)d_in[13];
  const float* b2  = (const float*)d_in[14];
  const float* g1  = (const float*)d_in[15];
  const float* be1 = (const float*)d_in[16];
  const float* g2  = (const float*)d_in[17];
  const float* be2 = (const float*)d_in[18];

  char* ws = (char*)d_ws;
  size_t off = 0;
  auto alloc = [&](size_t bytes) {
    void* p = ws + off;
    off += (bytes + 255) & ~(size_t)255;
    return p;
  };
  float* biasP  = (float*)alloc((size_t)2 * 1024 * 1024);  // 1MB used + prefetch pad
  float* mq     = (float*)alloc((size_t)N_ * 4);
  float* x      = (float*)alloc((size_t)ROWS * D_ * 4);
  bf16*  xb     = (bf16*) alloc((size_t)ROWS * D_ * 2);
  bf16*  attn_o = (bf16*) alloc((size_t)ROWS * D_ * 2);
  bf16*  qkv    = (bf16*) alloc((size_t)ROWS * 1024 * 2);  // shared: qkv[768] / ffn h1[1024]
  bf16*  h1     = qkv;
  bf16*  Wqkvt  = (bf16*) alloc((size_t)L_ * 768 * 256 * 2);
  bf16*  Wot    = (bf16*) alloc((size_t)L_ * 256 * 256 * 2);
  bf16*  W1t    = (bf16*) alloc((size_t)L_ * 1024 * 256 * 2);
  bf16*  W2t    = (bf16*) alloc((size_t)L_ * 256 * 1024 * 2);
  float* bqkv   = (float*)alloc((size_t)L_ * 768 * 4);

  bias_gemm<<<dim3(32, 32), dim3(16, 16), 0, stream>>>(e2, e1, biasP);
  colmax<<<2, 256, 0, stream>>>(biasP, mq);
  subm<<<256, 256, 0, stream>>>(biasP, mq);
  convT<<<dim3(8, 8, L_),  256, 0, stream>>>(Wq, Wqkvt,          256, 256, 65536, 196608);
  convT<<<dim3(8, 8, L_),  256, 0, stream>>>(Wk, Wqkvt + 65536,  256, 256, 65536, 196608);
  convT<<<dim3(8, 8, L_),  256, 0, stream>>>(Wv, Wqkvt + 131072, 256, 256, 65536, 196608);
  convT<<<dim3(8, 8, L_),  256, 0, stream>>>(Wo, Wot,            256, 256, 65536, 65536);
  convT<<<dim3(32, 8, L_), 256, 0, stream>>>(W1, W1t, 256, 1024, 262144, 262144);
  convT<<<dim3(8, 32, L_), 256, 0, stream>>>(W2, W2t, 1024, 256, 262144, 262144);
  pack_bqkv<<<12, 256, 0, stream>>>(bq, bk, bv, bqkv);
  init_x<<<ROWS * D_ / 1024, 256, 0, stream>>>(src, x, xb);

  for (int l = 0; l < L_; ++l) {
    gemm_bf16k<128, 0, 1><<<dim3(6, 128), 256, 0, stream>>>(
        xb, Wqkvt + (size_t)l * 196608, bqkv + l * 768, qkv, ROWS, 768, 256);
    attn_k<<<dim3(4, B_ * H_), 256, 0, stream>>>(qkv, biasP, attn_o);
    gemm_ln<<<256, 512, 0, stream>>>(
        attn_o, Wot + (size_t)l * 65536, bo + l * 256, x,
        g1 + l * 256, be1 + l * 256, x, xb, 256);
    gemm_bf16k<128, 1, 1><<<dim3(8, 128), 256, 0, stream>>>(
        xb, W1t + (size_t)l * 262144, b1 + l * 1024, h1, ROWS, 1024, 256);
    float* xout = (l == L_ - 1) ? (float*)d_out : x;
    gemm_ln<<<256, 512, 0, stream>>>(
        h1, W2t + (size_t)l * 262144, b2 + l * 256, x,
        g2 + l * 256, be2 + l * 256, xout, xb, 1024);
  }
}

// Round 5
// 582.578 us; speedup vs baseline: 1.0278x; 1.0278x over previous
//
#include <hip/hip_runtime.h>

typedef __bf16 bf16;
typedef __bf16 v8bf __attribute__((ext_vector_type(8)));
typedef float  v4f  __attribute__((ext_vector_type(4)));
typedef float  v16f __attribute__((ext_vector_type(16)));
typedef unsigned short u16;
typedef u16 v8us __attribute__((ext_vector_type(8)));
typedef unsigned int v4u __attribute__((ext_vector_type(4)));

#define L_ 4
#define B_ 32
#define N_ 512
#define D_ 256
#define H_ 8
#define F_ 1024
#define ROWS (B_*N_)   // 16384

__device__ __forceinline__ void gload16(const void* g, void* l) {
  __builtin_amdgcn_global_load_lds((__attribute__((address_space(1))) void*)g,
                                   (__attribute__((address_space(3))) void*)l,
                                   16, 0, 0);
}

__device__ __forceinline__ unsigned pk_bf16(float a, float b) {
  unsigned r;
  asm("v_cvt_pk_bf16_f32 %0, %1, %2" : "=v"(r) : "v"(a), "v"(b));
  return r;
}

#define EXP2(x) __builtin_amdgcn_exp2f(x)

// ---------------- biasP (permuted, MFMA C-layout) = (e2 @ e1^T) * log2e ----------------
// biasP float4 layout: [blk = kb*8 + g*2 + hi][q=512] of float4 over j
// where k-row = kb*32 + 8g + 4hi + j
__global__ __launch_bounds__(256) void bias_gemm(
    const float* __restrict__ e1, const float* __restrict__ e2,
    float* __restrict__ biasP) {
  __shared__ float As[16][16];
  __shared__ float Bs[16][16];
  const int tx = threadIdx.x, ty = threadIdx.y;
  const int r = blockIdx.y * 16 + ty, c = blockIdx.x * 16 + tx;
  float acc = 0.f;
  for (int k0 = 0; k0 < D_; k0 += 16) {
    As[ty][tx] = e1[r * D_ + k0 + tx];
    Bs[ty][tx] = e2[(blockIdx.x * 16 + ty) * D_ + k0 + tx];
    __syncthreads();
#pragma unroll
    for (int kk = 0; kk < 16; ++kk) acc += As[ty][kk] * Bs[tx][kk];
    __syncthreads();
  }
  const int kb = r >> 5, r5 = r & 31;
  const int blk = kb * 8 + (r5 >> 3) * 2 + ((r5 >> 2) & 1);
  biasP[(size_t)(blk * 512 + c) * 4 + (r5 & 3)] = acc * 1.4426950408889634f;
}

// ---------------- mq[q] = max over all k of biasP ----------------
__global__ __launch_bounds__(256) void colmax(
    const float* __restrict__ biasP, float* __restrict__ mq) {
  const int q = blockIdx.x * 256 + threadIdx.x;
  float mx = -1e30f;
  for (int blk = 0; blk < 128; ++blk) {
    const float4 v = *(const float4*)&biasP[(size_t)(blk * 512 + q) * 4];
    mx = fmaxf(mx, fmaxf(fmaxf(v.x, v.y), fmaxf(v.z, v.w)));
  }
  mq[q] = mx;
}

// ---------------- biasP -= mq[q] ----------------
__global__ __launch_bounds__(256) void subm(
    float* __restrict__ biasP, const float* __restrict__ mq) {
  const int i = blockIdx.x * 256 + threadIdx.x;  // 65536 float4
  float4 v = ((float4*)biasP)[i];
  const float m = mq[i & 511];
  v.x -= m; v.y -= m; v.z -= m; v.w -= m;
  ((float4*)biasP)[i] = v;
}

// ---------------- tiled weight transpose + bf16 cast: [K][N] -> [N][K] ----------------
__global__ __launch_bounds__(256) void convT(
    const float* __restrict__ W, bf16* __restrict__ Wt,
    int K, int N, size_t inL, size_t outL) {
  __shared__ float t[32][33];
  const int l = blockIdx.z;
  const int k0 = blockIdx.y * 32, n0 = blockIdx.x * 32;
  const int r = threadIdx.x >> 5, c = threadIdx.x & 31;
#pragma unroll
  for (int i = 0; i < 4; ++i)
    t[r + 8 * i][c] = W[l * inL + (size_t)(k0 + r + 8 * i) * N + n0 + c];
  __syncthreads();
#pragma unroll
  for (int i = 0; i < 4; ++i)
    Wt[l * outL + (size_t)(n0 + r + 8 * i) * K + k0 + c] = (bf16)t[c][r + 8 * i];
}

__global__ __launch_bounds__(256) void pack_bqkv(
    const float* __restrict__ bq, const float* __restrict__ bk,
    const float* __restrict__ bv, float* __restrict__ bqkv) {
  const int i = blockIdx.x * 256 + threadIdx.x;
  if (i < L_ * 768) {
    const int l = i / 768, n = i - l * 768;
    float v = (n < 256) ? bq[l * 256 + n]
            : (n < 512) ? bk[l * 256 + n - 256]
                        : bv[l * 256 + n - 512];
    bqkv[i] = v;
  }
}

__global__ __launch_bounds__(256) void init_x(
    const float* __restrict__ src, float* __restrict__ x,
    bf16* __restrict__ xb) {
  const int i = blockIdx.x * 256 + threadIdx.x;  // float4 index
  float4 v = ((const float4*)src)[i];
  ((float4*)x)[i] = v;
  uint2 w;
  w.x = pk_bf16(v.x, v.y);
  w.y = pk_bf16(v.z, v.w);
  ((uint2*)xb)[i] = w;
}

// ---------------- bf16 MFMA GEMM: C[M][N] = A[M][K] @ Bt[N][K]^T + bias ----------------
// tile BM x BN, 4 waves in 2x2
template <int BM, int BN, int RELU, int OUTBF16>
__global__ __launch_bounds__(256, 3) void gemm_bf16k(
    const bf16* __restrict__ A, const bf16* __restrict__ Bt,
    const float* __restrict__ bias, void* __restrict__ Cout,
    int M, int N, int K) {
  constexpr int MR = BM / 32, NR = BN / 32;
  constexpr int NSLAB = (BM + BN) / 16;
  __shared__ __align__(16) bf16 As[BM * 32];
  __shared__ __align__(16) bf16 Bs[BN * 32];
  const int tid  = threadIdx.x;
  const int wave = tid >> 6, lane = tid & 63;
  const int l15 = lane & 15, l4 = lane >> 4;
  const int bm = blockIdx.y * BM, bn = blockIdx.x * BN;
  const int wr = (wave >> 1) * (BM / 2), wc = (wave & 1) * (BN / 2);
  const int lrow = lane >> 2;
  const int lk   = (lane & 3) * 8;

  v4f acc[MR][NR];
#pragma unroll
  for (int m = 0; m < MR; ++m)
#pragma unroll
    for (int n = 0; n < NR; ++n) acc[m][n] = (v4f){0.f, 0.f, 0.f, 0.f};

  for (int k0 = 0; k0 < K; k0 += 32) {
#pragma unroll
    for (int s = wave; s < NSLAB; s += 4) {
      if (s < BM / 16)
        gload16(A + (size_t)(bm + s * 16 + lrow) * K + k0 + lk, &As[s * 512]);
      else {
        const int sb = s - BM / 16;
        gload16(Bt + (size_t)(bn + sb * 16 + lrow) * K + k0 + lk, &Bs[sb * 512]);
      }
    }
    __syncthreads();
    v8bf af[MR], bfr[NR];
#pragma unroll
    for (int m = 0; m < MR; ++m)
      af[m] = *(const v8bf*)&As[(wr + m * 16 + l15) * 32 + l4 * 8];
#pragma unroll
    for (int n = 0; n < NR; ++n)
      bfr[n] = *(const v8bf*)&Bs[(wc + n * 16 + l15) * 32 + l4 * 8];
#pragma unroll
    for (int m = 0; m < MR; ++m)
#pragma unroll
      for (int n = 0; n < NR; ++n)
        acc[m][n] = __builtin_amdgcn_mfma_f32_16x16x32_bf16(af[m], bfr[n], acc[m][n], 0, 0, 0);
    __syncthreads();
  }

#pragma unroll
  for (int m = 0; m < MR; ++m) {
    const int row0 = bm + wr + m * 16 + l4 * 4;
#pragma unroll
    for (int n = 0; n < NR; ++n) {
      const int col = bn + wc + n * 16 + l15;
      const float bc = bias[col];
#pragma unroll
      for (int i = 0; i < 4; ++i) {
        float v = acc[m][n][i] + bc;
        if (RELU) v = fmaxf(v, 0.f);
        const size_t idx = (size_t)(row0 + i) * N + col;
        if (OUTBF16) ((bf16*)Cout)[idx] = (bf16)v;
        else         ((float*)Cout)[idx] = v;
      }
    }
  }
}

// ---------------- fused flash attention, swapped-operand 32x32, fixed normalizer ----------------
// qkv: [B*N][768] bf16; biasP: permuted C-layout table (pre-max-subtracted, *log2e)
// XCD-aware 1D grid: each XCD owns 4 whole batches (qkv rows L2-resident).
#define VTS 520
__global__ __launch_bounds__(256, 4) void attn_k(
    const bf16* __restrict__ qkv, const float* __restrict__ biasP,
    bf16* __restrict__ outp) {
  __shared__ u16 Vt[32 * VTS];   // V^T: [d][kc]
  const int tid = threadIdx.x;
  const int wave = tid >> 6, lane = tid & 63;
  const int l31 = lane & 31, hi = lane >> 5;
  // swizzle: fid -> (xcd, idx); xcd owns b in [4*xcd, 4*xcd+4)
  const int fid = blockIdx.x;
  const int xcd = fid & 7, idx = fid >> 3;
  const int b = (xcd << 2) | (idx >> 5);
  const int h = (idx & 31) >> 2;
  const int qblk = idx & 3;
  const u16* base = (const u16*)qkv + (size_t)b * N_ * 768;
  const int qb = qblk * 128 + wave * 32;

  // ---- stage V^T (once per block): thread t packs rows 2t,2t+1 ----
  {
    const u16* vb = base + 512 + h * 32;
    const u16* p0 = vb + (size_t)(2 * tid) * 768;
    const u16* p1 = p0 + 768;
#pragma unroll
    for (int d0 = 0; d0 < 32; d0 += 8) {
      v8us a = *(const v8us*)(p0 + d0);
      v8us c = *(const v8us*)(p1 + d0);
#pragma unroll
      for (int j = 0; j < 8; ++j) {
        unsigned u = (unsigned)a[j] | ((unsigned)c[j] << 16);
        *(unsigned*)&Vt[(d0 + j) * VTS + tid * 2] = u;
      }
    }
  }
  __syncthreads();

  // ---- Q fragments (B operand), held all chunks ----
  const u16* qrow = base + (size_t)(qb + l31) * 768 + h * 32;
  const v8bf qf0 = *(const v8bf*)(qrow + hi * 8);
  const v8bf qf1 = *(const v8bf*)(qrow + 16 + hi * 8);
  const u16* kvb = base + 256 + h * 32;
  const float* bpl = biasP + ((size_t)(hi * 512 + qb + l31)) * 4;

  const float SC2 = 0.17677669529663688f * 1.4426950408889634f;
  float lsum = 0.f;
  v16f accO = {0.f,0.f,0.f,0.f,0.f,0.f,0.f,0.f,0.f,0.f,0.f,0.f,0.f,0.f,0.f,0.f};

  // prefetch chunk 0
  v8bf ka0 = *(const v8bf*)(kvb + (size_t)l31 * 768 + hi * 8);
  v8bf ka1 = *(const v8bf*)(kvb + (size_t)l31 * 768 + 16 + hi * 8);
  v4f bb[4];
#pragma unroll
  for (int g = 0; g < 4; ++g) bb[g] = *(const v4f*)(bpl + (size_t)(g * 2) * 2048);

  for (int kb = 0; kb < 16; ++kb) {
    const int kbase = kb * 32;
    v16f st = {0.f,0.f,0.f,0.f,0.f,0.f,0.f,0.f,0.f,0.f,0.f,0.f,0.f,0.f,0.f,0.f};
    st = __builtin_amdgcn_mfma_f32_32x32x16_bf16(ka0, qf0, st, 0, 0, 0);
    st = __builtin_amdgcn_mfma_f32_32x32x16_bf16(ka1, qf1, st, 0, 0, 0);

    // prefetch next chunk (unconditional; buffers padded)
    const u16* kn = kvb + (size_t)(kbase + 32 + l31) * 768;
    const v8bf kn0 = *(const v8bf*)(kn + hi * 8);
    const v8bf kn1 = *(const v8bf*)(kn + 16 + hi * 8);
    v4f bn[4];
#pragma unroll
    for (int g = 0; g < 4; ++g)
      bn[g] = *(const v4f*)(bpl + (size_t)((kb + 1) * 8 + g * 2) * 2048);

    // p = exp2(st*scale*log2e + biasP)
    float p[16];
#pragma unroll
    for (int r = 0; r < 16; ++r)
      p[r] = EXP2(st[r] * SC2 + bb[r >> 2][r & 3]);

    // lane-local partial sum
    float s8[8], s4[4];
#pragma unroll
    for (int r = 0; r < 8; ++r) s8[r] = p[r] + p[r + 8];
#pragma unroll
    for (int r = 0; r < 4; ++r) s4[r] = s8[r] + s8[r + 4];
    lsum += (s4[0] + s4[2]) + (s4[1] + s4[3]);

    // P -> bf16, redistribute into PV B-fragments
    unsigned u[8], x[8];
#pragma unroll
    for (int t = 0; t < 8; ++t) {
      u[t] = pk_bf16(p[2 * t], p[2 * t + 1]);
      x[t] = (unsigned)__shfl_xor((int)u[t], 32);
    }
    v4u b0 = (v4u){hi ? x[2] : u[0], hi ? x[3] : u[1], hi ? u[2] : x[0], hi ? u[3] : x[1]};
    v4u b1 = (v4u){hi ? x[6] : u[4], hi ? x[7] : u[5], hi ? u[6] : x[4], hi ? u[7] : x[5]};
    union { v4u u; v8bf h; } cv0, cv1;
    cv0.u = b0; cv1.u = b1;

    const v8bf va0 = *(const v8bf*)&Vt[l31 * VTS + kbase + hi * 8];
    const v8bf va1 = *(const v8bf*)&Vt[l31 * VTS + kbase + 16 + hi * 8];
    accO = __builtin_amdgcn_mfma_f32_32x32x16_bf16(va0, cv0.h, accO, 0, 0, 0);
    accO = __builtin_amdgcn_mfma_f32_32x32x16_bf16(va1, cv1.h, accO, 0, 0, 0);

    ka0 = kn0; ka1 = kn1;
#pragma unroll
    for (int g = 0; g < 4; ++g) bb[g] = bn[g];
  }

  lsum += __shfl_xor(lsum, 32);

  // ---- epilogue: O^T[d][q] regs -> out[q][h*32+d] ----
  const float inv = 1.0f / lsum;
  u16* orow = (u16*)outp + (size_t)(b * N_ + qb + l31) * D_ + h * 32 + 4 * hi;
#pragma unroll
  for (int g = 0; g < 4; ++g) {
    uint2 w;
    w.x = pk_bf16(accO[4 * g] * inv, accO[4 * g + 1] * inv);
    w.y = pk_bf16(accO[4 * g + 2] * inv, accO[4 * g + 3] * inv);
    *(uint2*)(orow + 8 * g) = w;
  }
}

// ---------------- residual + LayerNorm: 1 wave per row, 4 rows/block ----------------
__global__ __launch_bounds__(256) void ln_kernel(
    const float* __restrict__ xin, const float* __restrict__ add,
    const float* __restrict__ g, const float* __restrict__ b,
    float* __restrict__ xout, bf16* __restrict__ xbout) {
  const int wv = threadIdx.x >> 6, ln = threadIdx.x & 63;
  const size_t row = blockIdx.x * 4 + wv;
  const size_t o4 = row * D_ + ln * 4;
  const float4 xi = *(const float4*)&xin[o4];
  const float4 ad = *(const float4*)&add[o4];
  float4 v;
  v.x = xi.x + ad.x; v.y = xi.y + ad.y; v.z = xi.z + ad.z; v.w = xi.w + ad.w;
  float s  = (v.x + v.y) + (v.z + v.w);
  float ss = (v.x * v.x + v.y * v.y) + (v.z * v.z + v.w * v.w);
#pragma unroll
  for (int off = 1; off < 64; off <<= 1) {
    s  += __shfl_xor(s, off);
    ss += __shfl_xor(ss, off);
  }
  const float mu = s * (1.f / D_);
  const float var = ss * (1.f / D_) - mu * mu;
  const float rs = rsqrtf(var + 1e-5f);
  const float4 gg = *(const float4*)&g[ln * 4];
  const float4 bb = *(const float4*)&b[ln * 4];
  float4 o;
  o.x = (v.x - mu) * rs * gg.x + bb.x;
  o.y = (v.y - mu) * rs * gg.y + bb.y;
  o.z = (v.z - mu) * rs * gg.z + bb.z;
  o.w = (v.w - mu) * rs * gg.w + bb.w;
  *(float4*)&xout[o4] = o;
  uint2 w;
  w.x = pk_bf16(o.x, o.y);
  w.y = pk_bf16(o.z, o.w);
  *(uint2*)&xbout[o4] = w;
}

extern "C" void kernel_launch(void* const* d_in, const int* in_sizes, int n_in,
                              void* d_out, int out_size, void* d_ws, size_t ws_size,
                              hipStream_t stream) {
  const float* src = (const float*)d_in[0];
  const float* e1  = (const float*)d_in[1];
  const float* e2  = (const float*)d_in[2];
  const float* Wq  = (const float*)d_in[3];
  const float* bq  = (const float*)d_in[4];
  const float* Wk  = (const float*)d_in[5];
  const float* bk  = (const float*)d_in[6];
  const float* Wv  = (const float*)d_in[7];
  const float* bv  = (const float*)d_in[8];
  const float* Wo  = (const float*)d_in[9];
  const float* bo  = (const float*)d_in[10];
  const float* W1  = (const float*)d_in[11];
  const float* b1  = (const float*)d_in[12];
  const float* W2  = (const float*)d_in[13];
  const float* b2  = (const float*)d_in[14];
  const float* g1  = (const float*)d_in[15];
  const float* be1 = (const float*)d_in[16];
  const float* g2  = (const float*)d_in[17];
  const float* be2 = (const float*)d_in[18];

  char* ws = (char*)d_ws;
  size_t off = 0;
  auto alloc = [&](size_t bytes) {
    void* p = ws + off;
    off += (bytes + 255) & ~(size_t)255;
    return p;
  };
  float* biasP  = (float*)alloc((size_t)2 * 1024 * 1024);  // 1MB used + prefetch pad
  float* mq     = (float*)alloc((size_t)N_ * 4);
  float* x      = (float*)alloc((size_t)ROWS * D_ * 4);
  bf16*  xb     = (bf16*) alloc((size_t)ROWS * D_ * 2);
  bf16*  attn_o = (bf16*) alloc((size_t)ROWS * D_ * 2);
  float* tmp    = (float*)alloc((size_t)ROWS * D_ * 4);
  bf16*  qkv    = (bf16*) alloc((size_t)ROWS * 1024 * 2);  // shared: qkv[768] / ffn h1[1024]
  bf16*  h1     = qkv;
  bf16*  Wqkvt  = (bf16*) alloc((size_t)L_ * 768 * 256 * 2);
  bf16*  Wot    = (bf16*) alloc((size_t)L_ * 256 * 256 * 2);
  bf16*  W1t    = (bf16*) alloc((size_t)L_ * 1024 * 256 * 2);
  bf16*  W2t    = (bf16*) alloc((size_t)L_ * 256 * 1024 * 2);
  float* bqkv   = (float*)alloc((size_t)L_ * 768 * 4);

  bias_gemm<<<dim3(32, 32), dim3(16, 16), 0, stream>>>(e2, e1, biasP);
  colmax<<<2, 256, 0, stream>>>(biasP, mq);
  subm<<<256, 256, 0, stream>>>(biasP, mq);
  convT<<<dim3(8, 8, L_),  256, 0, stream>>>(Wq, Wqkvt,          256, 256, 65536, 196608);
  convT<<<dim3(8, 8, L_),  256, 0, stream>>>(Wk, Wqkvt + 65536,  256, 256, 65536, 196608);
  convT<<<dim3(8, 8, L_),  256, 0, stream>>>(Wv, Wqkvt + 131072, 256, 256, 65536, 196608);
  convT<<<dim3(8, 8, L_),  256, 0, stream>>>(Wo, Wot,            256, 256, 65536, 65536);
  convT<<<dim3(32, 8, L_), 256, 0, stream>>>(W1, W1t, 256, 1024, 262144, 262144);
  convT<<<dim3(8, 32, L_), 256, 0, stream>>>(W2, W2t, 1024, 256, 262144, 262144);
  pack_bqkv<<<12, 256, 0, stream>>>(bq, bk, bv, bqkv);
  init_x<<<ROWS * D_ / 1024, 256, 0, stream>>>(src, x, xb);

  for (int l = 0; l < L_; ++l) {
    gemm_bf16k<128, 128, 0, 1><<<dim3(6, 128), 256, 0, stream>>>(
        xb, Wqkvt + (size_t)l * 196608, bqkv + l * 768, qkv, ROWS, 768, 256);
    attn_k<<<1024, 256, 0, stream>>>(qkv, biasP, attn_o);
    gemm_bf16k<64, 64, 0, 0><<<dim3(4, 256), 256, 0, stream>>>(
        attn_o, Wot + (size_t)l * 65536, bo + l * 256, tmp, ROWS, 256, 256);
    ln_kernel<<<ROWS / 4, 256, 0, stream>>>(x, tmp, g1 + l * 256, be1 + l * 256, x, xb);
    gemm_bf16k<128, 128, 1, 1><<<dim3(8, 128), 256, 0, stream>>>(
        xb, W1t + (size_t)l * 262144, b1 + l * 1024, h1, ROWS, 1024, 256);
    gemm_bf16k<64, 64, 0, 0><<<dim3(4, 256), 256, 0, stream>>>(
        h1, W2t + (size_t)l * 262144, b2 + l * 256, tmp, ROWS, 256, 1024);
    float* xout = (l == L_ - 1) ? (float*)d_out : x;
    ln_kernel<<<ROWS / 4, 256, 0, stream>>>(x, tmp, g2 + l * 256, be2 + l * 256, xout, xb);
  }
}

// Round 6
// 552.992 us; speedup vs baseline: 1.0828x; 1.0535x over previous
//
#include <hip/hip_runtime.h>

typedef __bf16 bf16;
typedef __bf16 v8bf __attribute__((ext_vector_type(8)));
typedef float  v4f  __attribute__((ext_vector_type(4)));
typedef float  v16f __attribute__((ext_vector_type(16)));
typedef unsigned short u16;
typedef u16 v8us __attribute__((ext_vector_type(8)));
typedef unsigned int v4u __attribute__((ext_vector_type(4)));

#define L_ 4
#define B_ 32
#define N_ 512
#define D_ 256
#define H_ 8
#define F_ 1024
#define ROWS (B_*N_)   // 16384

__device__ __forceinline__ void gload16(const void* g, void* l) {
  __builtin_amdgcn_global_load_lds((__attribute__((address_space(1))) void*)g,
                                   (__attribute__((address_space(3))) void*)l,
                                   16, 0, 0);
}

__device__ __forceinline__ unsigned pk_bf16(float a, float b) {
  unsigned r;
  asm("v_cvt_pk_bf16_f32 %0, %1, %2" : "=v"(r) : "v"(a), "v"(b));
  return r;
}

#define EXP2(x) __builtin_amdgcn_exp2f(x)

// ---------------- biasP (permuted, MFMA C-layout) = (e2 @ e1^T) * log2e ----------------
__global__ __launch_bounds__(256) void bias_gemm(
    const float* __restrict__ e1, const float* __restrict__ e2,
    float* __restrict__ biasP) {
  __shared__ float As[16][16];
  __shared__ float Bs[16][16];
  const int tx = threadIdx.x, ty = threadIdx.y;
  const int r = blockIdx.y * 16 + ty, c = blockIdx.x * 16 + tx;
  float acc = 0.f;
  for (int k0 = 0; k0 < D_; k0 += 16) {
    As[ty][tx] = e1[r * D_ + k0 + tx];
    Bs[ty][tx] = e2[(blockIdx.x * 16 + ty) * D_ + k0 + tx];
    __syncthreads();
#pragma unroll
    for (int kk = 0; kk < 16; ++kk) acc += As[ty][kk] * Bs[tx][kk];
    __syncthreads();
  }
  const int kb = r >> 5, r5 = r & 31;
  const int blk = kb * 8 + (r5 >> 3) * 2 + ((r5 >> 2) & 1);
  biasP[(size_t)(blk * 512 + c) * 4 + (r5 & 3)] = acc * 1.4426950408889634f;
}

// ---------------- mq[q] = max over all k of biasP ----------------
__global__ __launch_bounds__(256) void colmax(
    const float* __restrict__ biasP, float* __restrict__ mq) {
  const int q = blockIdx.x * 256 + threadIdx.x;
  float mx = -1e30f;
  for (int blk = 0; blk < 128; ++blk) {
    const float4 v = *(const float4*)&biasP[(size_t)(blk * 512 + q) * 4];
    mx = fmaxf(mx, fmaxf(fmaxf(v.x, v.y), fmaxf(v.z, v.w)));
  }
  mq[q] = mx;
}

// ---------------- biasP -= mq[q] ----------------
__global__ __launch_bounds__(256) void subm(
    float* __restrict__ biasP, const float* __restrict__ mq) {
  const int i = blockIdx.x * 256 + threadIdx.x;  // 65536 float4
  float4 v = ((float4*)biasP)[i];
  const float m = mq[i & 511];
  v.x -= m; v.y -= m; v.z -= m; v.w -= m;
  ((float4*)biasP)[i] = v;
}

// ---------------- tiled weight transpose + bf16 cast: [K][N] -> [N][K] ----------------
__global__ __launch_bounds__(256) void convT(
    const float* __restrict__ W, bf16* __restrict__ Wt,
    int K, int N, size_t inL, size_t outL) {
  __shared__ float t[32][33];
  const int l = blockIdx.z;
  const int k0 = blockIdx.y * 32, n0 = blockIdx.x * 32;
  const int r = threadIdx.x >> 5, c = threadIdx.x & 31;
#pragma unroll
  for (int i = 0; i < 4; ++i)
    t[r + 8 * i][c] = W[l * inL + (size_t)(k0 + r + 8 * i) * N + n0 + c];
  __syncthreads();
#pragma unroll
  for (int i = 0; i < 4; ++i)
    Wt[l * outL + (size_t)(n0 + r + 8 * i) * K + k0 + c] = (bf16)t[c][r + 8 * i];
}

__global__ __launch_bounds__(256) void pack_bqkv(
    const float* __restrict__ bq, const float* __restrict__ bk,
    const float* __restrict__ bv, float* __restrict__ bqkv) {
  const int i = blockIdx.x * 256 + threadIdx.x;
  if (i < L_ * 768) {
    const int l = i / 768, n = i - l * 768;
    float v = (n < 256) ? bq[l * 256 + n]
            : (n < 512) ? bk[l * 256 + n - 256]
                        : bv[l * 256 + n - 512];
    bqkv[i] = v;
  }
}

__global__ __launch_bounds__(256) void init_x(
    const float* __restrict__ src, float* __restrict__ x,
    bf16* __restrict__ xb) {
  const int i = blockIdx.x * 256 + threadIdx.x;  // float4 index
  float4 v = ((const float4*)src)[i];
  ((float4*)x)[i] = v;
  uint2 w;
  w.x = pk_bf16(v.x, v.y);
  w.y = pk_bf16(v.z, v.w);
  ((uint2*)xb)[i] = w;
}

// ---------------- bf16 MFMA GEMM, 2-phase pipelined (T3min+T4), XCD-swizzled ----------------
// C[M][N] = A[M][K] @ Bt[N][K]^T + bias (+resid); 1D grid (multiple of 8), nbx passed.
template <int BM, int BN, int RELU, int OUTBF16, int RESID>
__global__ __launch_bounds__(256, 3) void gemm_bf16k(
    const bf16* __restrict__ A, const bf16* __restrict__ Bt,
    const float* __restrict__ bias, const float* __restrict__ resid,
    void* __restrict__ Cout, int M, int N, int K, int nbx) {
  constexpr int MR = BM / 32, NR = BN / 32;
  constexpr int NSLAB = (BM + BN) / 16;   // 16-row x 32-col slabs per tile
  constexpr int LPW = NSLAB / 4;          // gload16 per wave per stage
  constexpr int BUFE = (BM + BN) * 32;    // bf16 elems per LDS buffer
  __shared__ __align__(16) bf16 lds[3 * BUFE];
  const int tid  = threadIdx.x;
  const int wave = tid >> 6, lane = tid & 63;
  const int l15 = lane & 15, l4 = lane >> 4;
  // bijective XCD swizzle (gridDim.x % 8 == 0)
  const int qq = gridDim.x >> 3;
  const int wg = (blockIdx.x & 7) * qq + (blockIdx.x >> 3);
  const int bx = wg % nbx, by = wg / nbx;
  const int bm = by * BM, bn = bx * BN;
  const int wr = (wave >> 1) * (BM / 2), wc = (wave & 1) * (BN / 2);
  const int lrow = lane >> 2;         // row within 16-row slab
  const int lk   = (lane & 3) * 8;    // col offset

  v4f acc[MR][NR];
#pragma unroll
  for (int m = 0; m < MR; ++m)
#pragma unroll
    for (int n = 0; n < NR; ++n) acc[m][n] = (v4f){0.f, 0.f, 0.f, 0.f};

  auto STAGE = [&](int buf, int k0) {
    bf16* dst = &lds[buf * BUFE];
#pragma unroll
    for (int s = wave; s < NSLAB; s += 4) {
      if (s < BM / 16)
        gload16(A + (size_t)(bm + s * 16 + lrow) * K + k0 + lk, dst + s * 512);
      else
        gload16(Bt + (size_t)(bn + (s - BM / 16) * 16 + lrow) * K + k0 + lk, dst + s * 512);
    }
  };

  const int nk = K >> 5;
  STAGE(0, 0);
  STAGE(1, 32);
  if constexpr (LPW == 4) asm volatile("s_waitcnt vmcnt(4)" ::: "memory");
  else                    asm volatile("s_waitcnt vmcnt(2)" ::: "memory");
  __builtin_amdgcn_s_barrier();
  __builtin_amdgcn_sched_barrier(0);

  int cur = 0;
  for (int t = 0; t < nk; ++t) {
    const bool pf = (t + 2 < nk);
    if (pf) STAGE(cur == 0 ? 2 : cur - 1, (t + 2) * 32);
    const bf16* buf = &lds[cur * BUFE];
    v8bf af[MR], bfr[NR];
#pragma unroll
    for (int m = 0; m < MR; ++m)
      af[m] = *(const v8bf*)&buf[(wr + m * 16 + l15) * 32 + l4 * 8];
#pragma unroll
    for (int n = 0; n < NR; ++n)
      bfr[n] = *(const v8bf*)&buf[BM * 32 + (wc + n * 16 + l15) * 32 + l4 * 8];
    __builtin_amdgcn_s_setprio(1);
#pragma unroll
    for (int m = 0; m < MR; ++m)
#pragma unroll
      for (int n = 0; n < NR; ++n)
        acc[m][n] = __builtin_amdgcn_mfma_f32_16x16x32_bf16(af[m], bfr[n], acc[m][n], 0, 0, 0);
    __builtin_amdgcn_s_setprio(0);
    if (pf) {
      if constexpr (LPW == 4) asm volatile("s_waitcnt vmcnt(4)" ::: "memory");
      else                    asm volatile("s_waitcnt vmcnt(2)" ::: "memory");
    } else {
      asm volatile("s_waitcnt vmcnt(0)" ::: "memory");
    }
    __builtin_amdgcn_s_barrier();
    __builtin_amdgcn_sched_barrier(0);
    cur = (cur == 2) ? 0 : cur + 1;
  }

#pragma unroll
  for (int m = 0; m < MR; ++m) {
    const int row0 = bm + wr + m * 16 + l4 * 4;
#pragma unroll
    for (int n = 0; n < NR; ++n) {
      const int col = bn + wc + n * 16 + l15;
      const float bc = bias[col];
#pragma unroll
      for (int i = 0; i < 4; ++i) {
        const size_t idx = (size_t)(row0 + i) * N + col;
        float v = acc[m][n][i] + bc;
        if (RESID) v += resid[idx];
        if (RELU) v = fmaxf(v, 0.f);
        if (OUTBF16) ((bf16*)Cout)[idx] = (bf16)v;
        else         ((float*)Cout)[idx] = v;
      }
    }
  }
}

// ---------------- fused flash attention, swapped-operand 32x32, fixed normalizer ----------------
#define VTS 520
__global__ __launch_bounds__(256, 4) void attn_k(
    const bf16* __restrict__ qkv, const float* __restrict__ biasP,
    bf16* __restrict__ outp) {
  __shared__ u16 Vt[32 * VTS];   // V^T: [d][kc]
  const int tid = threadIdx.x;
  const int wave = tid >> 6, lane = tid & 63;
  const int l31 = lane & 31, hi = lane >> 5;
  const int fid = blockIdx.x;
  const int xcd = fid & 7, idx = fid >> 3;
  const int b = (xcd << 2) | (idx >> 5);
  const int h = (idx & 31) >> 2;
  const int qblk = idx & 3;
  const u16* base = (const u16*)qkv + (size_t)b * N_ * 768;
  const int qb = qblk * 128 + wave * 32;

  {
    const u16* vb = base + 512 + h * 32;
    const u16* p0 = vb + (size_t)(2 * tid) * 768;
    const u16* p1 = p0 + 768;
#pragma unroll
    for (int d0 = 0; d0 < 32; d0 += 8) {
      v8us a = *(const v8us*)(p0 + d0);
      v8us c = *(const v8us*)(p1 + d0);
#pragma unroll
      for (int j = 0; j < 8; ++j) {
        unsigned u = (unsigned)a[j] | ((unsigned)c[j] << 16);
        *(unsigned*)&Vt[(d0 + j) * VTS + tid * 2] = u;
      }
    }
  }
  __syncthreads();

  const u16* qrow = base + (size_t)(qb + l31) * 768 + h * 32;
  const v8bf qf0 = *(const v8bf*)(qrow + hi * 8);
  const v8bf qf1 = *(const v8bf*)(qrow + 16 + hi * 8);
  const u16* kvb = base + 256 + h * 32;
  const float* bpl = biasP + ((size_t)(hi * 512 + qb + l31)) * 4;

  const float SC2 = 0.17677669529663688f * 1.4426950408889634f;
  float lsum = 0.f;
  v16f accO = {0.f,0.f,0.f,0.f,0.f,0.f,0.f,0.f,0.f,0.f,0.f,0.f,0.f,0.f,0.f,0.f};

  v8bf ka0 = *(const v8bf*)(kvb + (size_t)l31 * 768 + hi * 8);
  v8bf ka1 = *(const v8bf*)(kvb + (size_t)l31 * 768 + 16 + hi * 8);
  v4f bb[4];
#pragma unroll
  for (int g = 0; g < 4; ++g) bb[g] = *(const v4f*)(bpl + (size_t)(g * 2) * 2048);

  for (int kb = 0; kb < 16; ++kb) {
    const int kbase = kb * 32;
    v16f st = {0.f,0.f,0.f,0.f,0.f,0.f,0.f,0.f,0.f,0.f,0.f,0.f,0.f,0.f,0.f,0.f};
    __builtin_amdgcn_s_setprio(1);
    st = __builtin_amdgcn_mfma_f32_32x32x16_bf16(ka0, qf0, st, 0, 0, 0);
    st = __builtin_amdgcn_mfma_f32_32x32x16_bf16(ka1, qf1, st, 0, 0, 0);
    __builtin_amdgcn_s_setprio(0);

    const u16* kn = kvb + (size_t)(kbase + 32 + l31) * 768;
    const v8bf kn0 = *(const v8bf*)(kn + hi * 8);
    const v8bf kn1 = *(const v8bf*)(kn + 16 + hi * 8);
    v4f bn[4];
#pragma unroll
    for (int g = 0; g < 4; ++g)
      bn[g] = *(const v4f*)(bpl + (size_t)((kb + 1) * 8 + g * 2) * 2048);

    float p[16];
#pragma unroll
    for (int r = 0; r < 16; ++r)
      p[r] = EXP2(st[r] * SC2 + bb[r >> 2][r & 3]);

    float s8[8], s4[4];
#pragma unroll
    for (int r = 0; r < 8; ++r) s8[r] = p[r] + p[r + 8];
#pragma unroll
    for (int r = 0; r < 4; ++r) s4[r] = s8[r] + s8[r + 4];
    lsum += (s4[0] + s4[2]) + (s4[1] + s4[3]);

    unsigned u[8], x[8];
#pragma unroll
    for (int t = 0; t < 8; ++t) {
      u[t] = pk_bf16(p[2 * t], p[2 * t + 1]);
      x[t] = (unsigned)__shfl_xor((int)u[t], 32);
    }
    v4u b0 = (v4u){hi ? x[2] : u[0], hi ? x[3] : u[1], hi ? u[2] : x[0], hi ? u[3] : x[1]};
    v4u b1 = (v4u){hi ? x[6] : u[4], hi ? x[7] : u[5], hi ? u[6] : x[4], hi ? u[7] : x[5]};
    union { v4u u; v8bf h; } cv0, cv1;
    cv0.u = b0; cv1.u = b1;

    const v8bf va0 = *(const v8bf*)&Vt[l31 * VTS + kbase + hi * 8];
    const v8bf va1 = *(const v8bf*)&Vt[l31 * VTS + kbase + 16 + hi * 8];
    __builtin_amdgcn_s_setprio(1);
    accO = __builtin_amdgcn_mfma_f32_32x32x16_bf16(va0, cv0.h, accO, 0, 0, 0);
    accO = __builtin_amdgcn_mfma_f32_32x32x16_bf16(va1, cv1.h, accO, 0, 0, 0);
    __builtin_amdgcn_s_setprio(0);

    ka0 = kn0; ka1 = kn1;
#pragma unroll
    for (int g = 0; g < 4; ++g) bb[g] = bn[g];
  }

  lsum += __shfl_xor(lsum, 32);

  const float inv = 1.0f / lsum;
  u16* orow = (u16*)outp + (size_t)(b * N_ + qb + l31) * D_ + h * 32 + 4 * hi;
#pragma unroll
  for (int g = 0; g < 4; ++g) {
    uint2 w;
    w.x = pk_bf16(accO[4 * g] * inv, accO[4 * g + 1] * inv);
    w.y = pk_bf16(accO[4 * g + 2] * inv, accO[4 * g + 3] * inv);
    *(uint2*)(orow + 8 * g) = w;
  }
}

// ---------------- LayerNorm (input already has residual added): 1 wave/row, 4 rows/block ----------------
__global__ __launch_bounds__(256) void ln_kernel(
    const float* __restrict__ xin,
    const float* __restrict__ g, const float* __restrict__ b,
    float* __restrict__ xout, bf16* __restrict__ xbout) {
  const int wv = threadIdx.x >> 6, ln = threadIdx.x & 63;
  const size_t row = blockIdx.x * 4 + wv;
  const size_t o4 = row * D_ + ln * 4;
  const float4 v = *(const float4*)&xin[o4];
  float s  = (v.x + v.y) + (v.z + v.w);
  float ss = (v.x * v.x + v.y * v.y) + (v.z * v.z + v.w * v.w);
#pragma unroll
  for (int off = 1; off < 64; off <<= 1) {
    s  += __shfl_xor(s, off);
    ss += __shfl_xor(ss, off);
  }
  const float mu = s * (1.f / D_);
  const float var = ss * (1.f / D_) - mu * mu;
  const float rs = rsqrtf(var + 1e-5f);
  const float4 gg = *(const float4*)&g[ln * 4];
  const float4 bb = *(const float4*)&b[ln * 4];
  float4 o;
  o.x = (v.x - mu) * rs * gg.x + bb.x;
  o.y = (v.y - mu) * rs * gg.y + bb.y;
  o.z = (v.z - mu) * rs * gg.z + bb.z;
  o.w = (v.w - mu) * rs * gg.w + bb.w;
  *(float4*)&xout[o4] = o;
  uint2 w;
  w.x = pk_bf16(o.x, o.y);
  w.y = pk_bf16(o.z, o.w);
  *(uint2*)&xbout[o4] = w;
}

extern "C" void kernel_launch(void* const* d_in, const int* in_sizes, int n_in,
                              void* d_out, int out_size, void* d_ws, size_t ws_size,
                              hipStream_t stream) {
  const float* src = (const float*)d_in[0];
  const float* e1  = (const float*)d_in[1];
  const float* e2  = (const float*)d_in[2];
  const float* Wq  = (const float*)d_in[3];
  const float* bq  = (const float*)d_in[4];
  const float* Wk  = (const float*)d_in[5];
  const float* bk  = (const float*)d_in[6];
  const float* Wv  = (const float*)d_in[7];
  const float* bv  = (const float*)d_in[8];
  const float* Wo  = (const float*)d_in[9];
  const float* bo  = (const float*)d_in[10];
  const float* W1  = (const float*)d_in[11];
  const float* b1  = (const float*)d_in[12];
  const float* W2  = (const float*)d_in[13];
  const float* b2  = (const float*)d_in[14];
  const float* g1  = (const float*)d_in[15];
  const float* be1 = (const float*)d_in[16];
  const float* g2  = (const float*)d_in[17];
  const float* be2 = (const float*)d_in[18];

  char* ws = (char*)d_ws;
  size_t off = 0;
  auto alloc = [&](size_t bytes) {
    void* p = ws + off;
    off += (bytes + 255) & ~(size_t)255;
    return p;
  };
  float* biasP  = (float*)alloc((size_t)2 * 1024 * 1024);  // 1MB used + prefetch pad
  float* mq     = (float*)alloc((size_t)N_ * 4);
  float* x      = (float*)alloc((size_t)ROWS * D_ * 4);
  bf16*  xb     = (bf16*) alloc((size_t)ROWS * D_ * 2);
  bf16*  attn_o = (bf16*) alloc((size_t)ROWS * D_ * 2);
  float* tmp    = (float*)alloc((size_t)ROWS * D_ * 4);
  bf16*  qkv    = (bf16*) alloc((size_t)ROWS * 1024 * 2);  // shared: qkv[768] / ffn h1[1024]
  bf16*  h1     = qkv;
  bf16*  Wqkvt  = (bf16*) alloc((size_t)L_ * 768 * 256 * 2);
  bf16*  Wot    = (bf16*) alloc((size_t)L_ * 256 * 256 * 2);
  bf16*  W1t    = (bf16*) alloc((size_t)L_ * 1024 * 256 * 2);
  bf16*  W2t    = (bf16*) alloc((size_t)L_ * 256 * 1024 * 2);
  float* bqkv   = (float*)alloc((size_t)L_ * 768 * 4);

  bias_gemm<<<dim3(32, 32), dim3(16, 16), 0, stream>>>(e2, e1, biasP);
  colmax<<<2, 256, 0, stream>>>(biasP, mq);
  subm<<<256, 256, 0, stream>>>(biasP, mq);
  convT<<<dim3(8, 8, L_),  256, 0, stream>>>(Wq, Wqkvt,          256, 256, 65536, 196608);
  convT<<<dim3(8, 8, L_),  256, 0, stream>>>(Wk, Wqkvt + 65536,  256, 256, 65536, 196608);
  convT<<<dim3(8, 8, L_),  256, 0, stream>>>(Wv, Wqkvt + 131072, 256, 256, 65536, 196608);
  convT<<<dim3(8, 8, L_),  256, 0, stream>>>(Wo, Wot,            256, 256, 65536, 65536);
  convT<<<dim3(32, 8, L_), 256, 0, stream>>>(W1, W1t, 256, 1024, 262144, 262144);
  convT<<<dim3(8, 32, L_), 256, 0, stream>>>(W2, W2t, 1024, 256, 262144, 262144);
  pack_bqkv<<<12, 256, 0, stream>>>(bq, bk, bv, bqkv);
  init_x<<<ROWS * D_ / 1024, 256, 0, stream>>>(src, x, xb);

  for (int l = 0; l < L_; ++l) {
    // QKV: M=16384, N=768, K=256; grid 6*128=768 (%8==0)
    gemm_bf16k<128, 128, 0, 1, 0><<<768, 256, 0, stream>>>(
        xb, Wqkvt + (size_t)l * 196608, bqkv + l * 768, nullptr, qkv,
        ROWS, 768, 256, 6);
    attn_k<<<1024, 256, 0, stream>>>(qkv, biasP, attn_o);
    // Wo + residual: M=16384, N=256, K=256; grid 4*256=1024
    gemm_bf16k<64, 64, 0, 0, 1><<<1024, 256, 0, stream>>>(
        attn_o, Wot + (size_t)l * 65536, bo + l * 256, x, tmp,
        ROWS, 256, 256, 4);
    ln_kernel<<<ROWS / 4, 256, 0, stream>>>(tmp, g1 + l * 256, be1 + l * 256, x, xb);
    // W1 + ReLU: M=16384, N=1024, K=256; grid 8*128=1024
    gemm_bf16k<128, 128, 1, 1, 0><<<1024, 256, 0, stream>>>(
        xb, W1t + (size_t)l * 262144, b1 + l * 1024, nullptr, h1,
        ROWS, 1024, 256, 8);
    // W2 + residual: M=16384, N=256, K=1024; grid 4*256=1024
    gemm_bf16k<64, 64, 0, 0, 1><<<1024, 256, 0, stream>>>(
        h1, W2t + (size_t)l * 262144, b2 + l * 256, x, tmp,
        ROWS, 256, 1024, 4);
    float* xout = (l == L_ - 1) ? (float*)d_out : x;
    ln_kernel<<<ROWS / 4, 256, 0, stream>>>(tmp, g2 + l * 256, be2 + l * 256, xout, xb);
  }
}

// Round 7
// 544.245 us; speedup vs baseline: 1.1002x; 1.0161x over previous
//
#include <hip/hip_runtime.h>

typedef __bf16 bf16;
typedef __bf16 v8bf __attribute__((ext_vector_type(8)));
typedef float  v4f  __attribute__((ext_vector_type(4)));
typedef float  v16f __attribute__((ext_vector_type(16)));
typedef unsigned short u16;
typedef u16 v8us __attribute__((ext_vector_type(8)));
typedef unsigned int v4u __attribute__((ext_vector_type(4)));

#define L_ 4
#define B_ 32
#define N_ 512
#define D_ 256
#define H_ 8
#define F_ 1024
#define ROWS (B_*N_)   // 16384

__device__ __forceinline__ void gload16(const void* g, void* l) {
  __builtin_amdgcn_global_load_lds((__attribute__((address_space(1))) void*)g,
                                   (__attribute__((address_space(3))) void*)l,
                                   16, 0, 0);
}

__device__ __forceinline__ unsigned pk_bf16(float a, float b) {
  unsigned r;
  asm("v_cvt_pk_bf16_f32 %0, %1, %2" : "=v"(r) : "v"(a), "v"(b));
  return r;
}

// swap: a.hi <-> b.lo  (a' = {a.lo, b.lo-lanes}, b' = {a.hi-lanes, b.hi})
#define PLSWAP(a, b) asm volatile("v_permlane32_swap_b32 %0, %1" : "+v"(a), "+v"(b))

#define EXP2(x) __builtin_amdgcn_exp2f(x)

template <int N> __device__ __forceinline__ void waitvm() {
  if constexpr (N == 0) asm volatile("s_waitcnt vmcnt(0)" ::: "memory");
  else if constexpr (N == 2) asm volatile("s_waitcnt vmcnt(2)" ::: "memory");
  else if constexpr (N == 3) asm volatile("s_waitcnt vmcnt(3)" ::: "memory");
  else if constexpr (N == 4) asm volatile("s_waitcnt vmcnt(4)" ::: "memory");
  else if constexpr (N == 5) asm volatile("s_waitcnt vmcnt(5)" ::: "memory");
  else if constexpr (N == 6) asm volatile("s_waitcnt vmcnt(6)" ::: "memory");
}

// ---------------- biasP (permuted, MFMA C-layout) = (e2 @ e1^T) * log2e ----------------
__global__ __launch_bounds__(256) void bias_gemm(
    const float* __restrict__ e1, const float* __restrict__ e2,
    float* __restrict__ biasP) {
  __shared__ float As[16][16];
  __shared__ float Bs[16][16];
  const int tx = threadIdx.x, ty = threadIdx.y;
  const int r = blockIdx.y * 16 + ty, c = blockIdx.x * 16 + tx;
  float acc = 0.f;
  for (int k0 = 0; k0 < D_; k0 += 16) {
    As[ty][tx] = e1[r * D_ + k0 + tx];
    Bs[ty][tx] = e2[(blockIdx.x * 16 + ty) * D_ + k0 + tx];
    __syncthreads();
#pragma unroll
    for (int kk = 0; kk < 16; ++kk) acc += As[ty][kk] * Bs[tx][kk];
    __syncthreads();
  }
  const int kb = r >> 5, r5 = r & 31;
  const int blk = kb * 8 + (r5 >> 3) * 2 + ((r5 >> 2) & 1);
  biasP[(size_t)(blk * 512 + c) * 4 + (r5 & 3)] = acc * 1.4426950408889634f;
}

// ---------------- mq[q] = max over all k of biasP ----------------
__global__ __launch_bounds__(256) void colmax(
    const float* __restrict__ biasP, float* __restrict__ mq) {
  const int q = blockIdx.x * 256 + threadIdx.x;
  float mx = -1e30f;
  for (int blk = 0; blk < 128; ++blk) {
    const float4 v = *(const float4*)&biasP[(size_t)(blk * 512 + q) * 4];
    mx = fmaxf(mx, fmaxf(fmaxf(v.x, v.y), fmaxf(v.z, v.w)));
  }
  mq[q] = mx;
}

// ---------------- biasP -= mq[q] ----------------
__global__ __launch_bounds__(256) void subm(
    float* __restrict__ biasP, const float* __restrict__ mq) {
  const int i = blockIdx.x * 256 + threadIdx.x;  // 65536 float4
  float4 v = ((float4*)biasP)[i];
  const float m = mq[i & 511];
  v.x -= m; v.y -= m; v.z -= m; v.w -= m;
  ((float4*)biasP)[i] = v;
}

// ---------------- tiled weight transpose + bf16 cast: [K][N] -> [N][K] ----------------
__global__ __launch_bounds__(256) void convT(
    const float* __restrict__ W, bf16* __restrict__ Wt,
    int K, int N, size_t inL, size_t outL) {
  __shared__ float t[32][33];
  const int l = blockIdx.z;
  const int k0 = blockIdx.y * 32, n0 = blockIdx.x * 32;
  const int r = threadIdx.x >> 5, c = threadIdx.x & 31;
#pragma unroll
  for (int i = 0; i < 4; ++i)
    t[r + 8 * i][c] = W[l * inL + (size_t)(k0 + r + 8 * i) * N + n0 + c];
  __syncthreads();
#pragma unroll
  for (int i = 0; i < 4; ++i)
    Wt[l * outL + (size_t)(n0 + r + 8 * i) * K + k0 + c] = (bf16)t[c][r + 8 * i];
}

__global__ __launch_bounds__(256) void pack_bqkv(
    const float* __restrict__ bq, const float* __restrict__ bk,
    const float* __restrict__ bv, float* __restrict__ bqkv) {
  const int i = blockIdx.x * 256 + threadIdx.x;
  if (i < L_ * 768) {
    const int l = i / 768, n = i - l * 768;
    float v = (n < 256) ? bq[l * 256 + n]
            : (n < 512) ? bk[l * 256 + n - 256]
                        : bv[l * 256 + n - 512];
    bqkv[i] = v;
  }
}

__global__ __launch_bounds__(256) void init_x(
    const float* __restrict__ src, float* __restrict__ x,
    bf16* __restrict__ xb) {
  const int i = blockIdx.x * 256 + threadIdx.x;  // float4 index
  float4 v = ((const float4*)src)[i];
  ((float4*)x)[i] = v;
  uint2 w;
  w.x = pk_bf16(v.x, v.y);
  w.y = pk_bf16(v.z, v.w);
  ((uint2*)xb)[i] = w;
}

// ---------------- bf16 MFMA GEMM, 2-phase pipelined (T3min+T4), XCD-swizzled ----------------
// C[M][N] = A[M][K] @ Bt[N][K]^T + bias (+resid); 1D grid (multiple of 8), nbx passed.
template <int BM, int BN, int WPC, int RELU, int OUTBF16, int RESID>
__global__ __launch_bounds__(256, WPC) void gemm_bf16k(
    const bf16* __restrict__ A, const bf16* __restrict__ Bt,
    const float* __restrict__ bias, const float* __restrict__ resid,
    void* __restrict__ Cout, int M, int N, int K, int nbx) {
  constexpr int MR = BM / 32, NR = BN / 32;
  constexpr int NSLAB = (BM + BN) / 16;   // 16-row x 32-col slabs per tile
  constexpr int LPW = NSLAB / 4;          // gload16 per wave per stage
  constexpr int BUFE = (BM + BN) * 32;    // bf16 elems per LDS buffer
  __shared__ __align__(16) bf16 lds[3 * BUFE];
  const int tid  = threadIdx.x;
  const int wave = tid >> 6, lane = tid & 63;
  const int l15 = lane & 15, l4 = lane >> 4;
  // bijective XCD swizzle (gridDim.x % 8 == 0)
  const int qq = gridDim.x >> 3;
  const int wg = (blockIdx.x & 7) * qq + (blockIdx.x >> 3);
  const int bx = wg % nbx, by = wg / nbx;
  const int bm = by * BM, bn = bx * BN;
  const int wr = (wave >> 1) * (BM / 2), wc = (wave & 1) * (BN / 2);
  const int lrow = lane >> 2;         // row within 16-row slab
  const int lk   = (lane & 3) * 8;    // col offset

  v4f acc[MR][NR];
#pragma unroll
  for (int m = 0; m < MR; ++m)
#pragma unroll
    for (int n = 0; n < NR; ++n) acc[m][n] = (v4f){0.f, 0.f, 0.f, 0.f};

  auto STAGE = [&](int buf, int k0) {
    bf16* dst = &lds[buf * BUFE];
#pragma unroll
    for (int s = wave; s < NSLAB; s += 4) {
      if (s < BM / 16)
        gload16(A + (size_t)(bm + s * 16 + lrow) * K + k0 + lk, dst + s * 512);
      else
        gload16(Bt + (size_t)(bn + (s - BM / 16) * 16 + lrow) * K + k0 + lk, dst + s * 512);
    }
  };

  const int nk = K >> 5;
  STAGE(0, 0);
  STAGE(1, 32);
  waitvm<LPW>();
  __builtin_amdgcn_s_barrier();
  __builtin_amdgcn_sched_barrier(0);

  int cur = 0;
  for (int t = 0; t < nk; ++t) {
    const bool pf = (t + 2 < nk);
    if (pf) STAGE(cur == 0 ? 2 : cur - 1, (t + 2) * 32);
    const bf16* buf = &lds[cur * BUFE];
    v8bf af[MR], bfr[NR];
#pragma unroll
    for (int m = 0; m < MR; ++m)
      af[m] = *(const v8bf*)&buf[(wr + m * 16 + l15) * 32 + l4 * 8];
#pragma unroll
    for (int n = 0; n < NR; ++n)
      bfr[n] = *(const v8bf*)&buf[BM * 32 + (wc + n * 16 + l15) * 32 + l4 * 8];
    __builtin_amdgcn_s_setprio(1);
#pragma unroll
    for (int m = 0; m < MR; ++m)
#pragma unroll
      for (int n = 0; n < NR; ++n)
        acc[m][n] = __builtin_amdgcn_mfma_f32_16x16x32_bf16(af[m], bfr[n], acc[m][n], 0, 0, 0);
    __builtin_amdgcn_s_setprio(0);
    if (pf) waitvm<LPW>();
    else    waitvm<0>();
    __builtin_amdgcn_s_barrier();
    __builtin_amdgcn_sched_barrier(0);
    cur = (cur == 2) ? 0 : cur + 1;
  }

#pragma unroll
  for (int m = 0; m < MR; ++m) {
    const int row0 = bm + wr + m * 16 + l4 * 4;
#pragma unroll
    for (int n = 0; n < NR; ++n) {
      const int col = bn + wc + n * 16 + l15;
      const float bc = bias[col];
#pragma unroll
      for (int i = 0; i < 4; ++i) {
        const size_t idx = (size_t)(row0 + i) * N + col;
        float v = acc[m][n][i] + bc;
        if (RESID) v += resid[idx];
        if (RELU) v = fmaxf(v, 0.f);
        if (OUTBF16) ((bf16*)Cout)[idx] = (bf16)v;
        else         ((float*)Cout)[idx] = v;
      }
    }
  }
}

// ---------------- fused flash attention, swapped 32x32, fixed normalizer, 2-chunk pipeline ----------------
#define VTS 520
__global__ __launch_bounds__(256, 3) void attn_k(
    const bf16* __restrict__ qkv, const float* __restrict__ biasP,
    bf16* __restrict__ outp) {
  __shared__ u16 Vt[32 * VTS];   // V^T: [d][kc]
  const int tid = threadIdx.x;
  const int wave = tid >> 6, lane = tid & 63;
  const int l31 = lane & 31, hi = lane >> 5;
  const int fid = blockIdx.x;
  const int xcd = fid & 7, idx = fid >> 3;
  const int b = (xcd << 2) | (idx >> 5);
  const int h = (idx & 31) >> 2;
  const int qblk = idx & 3;
  const u16* base = (const u16*)qkv + (size_t)b * N_ * 768;
  const int qb = qblk * 128 + wave * 32;

  // ---- stage V^T (once per block): thread t packs rows 2t,2t+1 ----
  {
    const u16* vb = base + 512 + h * 32;
    const u16* p0 = vb + (size_t)(2 * tid) * 768;
    const u16* p1 = p0 + 768;
#pragma unroll
    for (int d0 = 0; d0 < 32; d0 += 8) {
      v8us a = *(const v8us*)(p0 + d0);
      v8us c = *(const v8us*)(p1 + d0);
#pragma unroll
      for (int j = 0; j < 8; ++j) {
        unsigned u = (unsigned)a[j] | ((unsigned)c[j] << 16);
        *(unsigned*)&Vt[(d0 + j) * VTS + tid * 2] = u;
      }
    }
  }
  __syncthreads();

  // ---- Q fragments (B operand), held all chunks ----
  const u16* qrow = base + (size_t)(qb + l31) * 768 + h * 32;
  const v8bf qf0 = *(const v8bf*)(qrow + hi * 8);
  const v8bf qf1 = *(const v8bf*)(qrow + 16 + hi * 8);
  const u16* kvb = base + 256 + h * 32;
  const float* bpl = biasP + ((size_t)(hi * 512 + qb + l31)) * 4;

  const float SC2 = 0.17677669529663688f * 1.4426950408889634f;
  float lsum = 0.f;
  v16f accO = {0.f,0.f,0.f,0.f,0.f,0.f,0.f,0.f,0.f,0.f,0.f,0.f,0.f,0.f,0.f,0.f};

  // chunk-0 operands
  v8bf ka0 = *(const v8bf*)(kvb + (size_t)l31 * 768 + hi * 8);
  v8bf ka1 = *(const v8bf*)(kvb + (size_t)l31 * 768 + 16 + hi * 8);
  v4f bb[4];
#pragma unroll
  for (int g = 0; g < 4; ++g) bb[g] = *(const v4f*)(bpl + (size_t)(g * 2) * 2048);

  // stC = QK^T(chunk 0)
  v16f stC = {0.f,0.f,0.f,0.f,0.f,0.f,0.f,0.f,0.f,0.f,0.f,0.f,0.f,0.f,0.f,0.f};
  stC = __builtin_amdgcn_mfma_f32_32x32x16_bf16(ka0, qf0, stC, 0, 0, 0);
  stC = __builtin_amdgcn_mfma_f32_32x32x16_bf16(ka1, qf1, stC, 0, 0, 0);
  // K(1)
  {
    const u16* kn = kvb + (size_t)(32 + l31) * 768;
    ka0 = *(const v8bf*)(kn + hi * 8);
    ka1 = *(const v8bf*)(kn + 16 + hi * 8);
  }

  for (int kb = 0; kb < 16; ++kb) {
    const int kbase = kb * 32;
    // issue QK^T(kb+1) early: MFMA pipe runs under softmax VALU of chunk kb
    v16f stN = {0.f,0.f,0.f,0.f,0.f,0.f,0.f,0.f,0.f,0.f,0.f,0.f,0.f,0.f,0.f,0.f};
    __builtin_amdgcn_s_setprio(1);
    stN = __builtin_amdgcn_mfma_f32_32x32x16_bf16(ka0, qf0, stN, 0, 0, 0);
    stN = __builtin_amdgcn_mfma_f32_32x32x16_bf16(ka1, qf1, stN, 0, 0, 0);
    __builtin_amdgcn_s_setprio(0);

    // prefetch K(kb+2) and bias(kb+1)  (unconditional; buffers padded)
    const u16* kn = kvb + (size_t)(kbase + 64 + l31) * 768;
    const v8bf kn0 = *(const v8bf*)(kn + hi * 8);
    const v8bf kn1 = *(const v8bf*)(kn + 16 + hi * 8);
    v4f bn[4];
#pragma unroll
    for (int g = 0; g < 4; ++g)
      bn[g] = *(const v4f*)(bpl + (size_t)((kb + 1) * 8 + g * 2) * 2048);

    // softmax (base-2, fixed normalizer) on chunk kb
    float p[16];
#pragma unroll
    for (int r = 0; r < 16; ++r)
      p[r] = EXP2(stC[r] * SC2 + bb[r >> 2][r & 3]);

    float s8[8], s4[4];
#pragma unroll
    for (int r = 0; r < 8; ++r) s8[r] = p[r] + p[r + 8];
#pragma unroll
    for (int r = 0; r < 4; ++r) s4[r] = s8[r] + s8[r + 4];
    lsum += (s4[0] + s4[2]) + (s4[1] + s4[3]);

    // P -> bf16 pairs, then permlane32_swap into PV B-fragments
    unsigned u[8];
#pragma unroll
    for (int t = 0; t < 8; ++t) u[t] = pk_bf16(p[2 * t], p[2 * t + 1]);
    PLSWAP(u[0], u[2]);
    PLSWAP(u[1], u[3]);
    PLSWAP(u[4], u[6]);
    PLSWAP(u[5], u[7]);
    union { v4u u; v8bf h; } cv0, cv1;
    cv0.u = (v4u){u[0], u[1], u[2], u[3]};
    cv1.u = (v4u){u[4], u[5], u[6], u[7]};

    const v8bf va0 = *(const v8bf*)&Vt[l31 * VTS + kbase + hi * 8];
    const v8bf va1 = *(const v8bf*)&Vt[l31 * VTS + kbase + 16 + hi * 8];
    __builtin_amdgcn_s_setprio(1);
    accO = __builtin_amdgcn_mfma_f32_32x32x16_bf16(va0, cv0.h, accO, 0, 0, 0);
    accO = __builtin_amdgcn_mfma_f32_32x32x16_bf16(va1, cv1.h, accO, 0, 0, 0);
    __builtin_amdgcn_s_setprio(0);

    stC = stN;
    ka0 = kn0; ka1 = kn1;
#pragma unroll
    for (int g = 0; g < 4; ++g) bb[g] = bn[g];
  }

  lsum += __shfl_xor(lsum, 32);

  // ---- epilogue: O^T[d][q] regs -> out[q][h*32+d] ----
  const float inv = 1.0f / lsum;
  u16* orow = (u16*)outp + (size_t)(b * N_ + qb + l31) * D_ + h * 32 + 4 * hi;
#pragma unroll
  for (int g = 0; g < 4; ++g) {
    uint2 w;
    w.x = pk_bf16(accO[4 * g] * inv, accO[4 * g + 1] * inv);
    w.y = pk_bf16(accO[4 * g + 2] * inv, accO[4 * g + 3] * inv);
    *(uint2*)(orow + 8 * g) = w;
  }
}

// ---------------- LayerNorm (input already has residual added): 1 wave/row, 4 rows/block ----------------
__global__ __launch_bounds__(256) void ln_kernel(
    const float* __restrict__ xin,
    const float* __restrict__ g, const float* __restrict__ b,
    float* __restrict__ xout, bf16* __restrict__ xbout) {
  const int wv = threadIdx.x >> 6, ln = threadIdx.x & 63;
  const size_t row = blockIdx.x * 4 + wv;
  const size_t o4 = row * D_ + ln * 4;
  const float4 v = *(const float4*)&xin[o4];
  float s  = (v.x + v.y) + (v.z + v.w);
  float ss = (v.x * v.x + v.y * v.y) + (v.z * v.z + v.w * v.w);
#pragma unroll
  for (int off = 1; off < 64; off <<= 1) {
    s  += __shfl_xor(s, off);
    ss += __shfl_xor(ss, off);
  }
  const float mu = s * (1.f / D_);
  const float var = ss * (1.f / D_) - mu * mu;
  const float rs = rsqrtf(var + 1e-5f);
  const float4 gg = *(const float4*)&g[ln * 4];
  const float4 bb = *(const float4*)&b[ln * 4];
  float4 o;
  o.x = (v.x - mu) * rs * gg.x + bb.x;
  o.y = (v.y - mu) * rs * gg.y + bb.y;
  o.z = (v.z - mu) * rs * gg.z + bb.z;
  o.w = (v.w - mu) * rs * gg.w + bb.w;
  *(float4*)&xout[o4] = o;
  uint2 w;
  w.x = pk_bf16(o.x, o.y);
  w.y = pk_bf16(o.z, o.w);
  *(uint2*)&xbout[o4] = w;
}

extern "C" void kernel_launch(void* const* d_in, const int* in_sizes, int n_in,
                              void* d_out, int out_size, void* d_ws, size_t ws_size,
                              hipStream_t stream) {
  const float* src = (const float*)d_in[0];
  const float* e1  = (const float*)d_in[1];
  const float* e2  = (const float*)d_in[2];
  const float* Wq  = (const float*)d_in[3];
  const float* bq  = (const float*)d_in[4];
  const float* Wk  = (const float*)d_in[5];
  const float* bk  = (const float*)d_in[6];
  const float* Wv  = (const float*)d_in[7];
  const float* bv  = (const float*)d_in[8];
  const float* Wo  = (const float*)d_in[9];
  const float* bo  = (const float*)d_in[10];
  const float* W1  = (const float*)d_in[11];
  const float* b1  = (const float*)d_in[12];
  const float* W2  = (const float*)d_in[13];
  const float* b2  = (const float*)d_in[14];
  const float* g1  = (const float*)d_in[15];
  const float* be1 = (const float*)d_in[16];
  const float* g2  = (const float*)d_in[17];
  const float* be2 = (const float*)d_in[18];

  char* ws = (char*)d_ws;
  size_t off = 0;
  auto alloc = [&](size_t bytes) {
    void* p = ws + off;
    off += (bytes + 255) & ~(size_t)255;
    return p;
  };
  float* biasP  = (float*)alloc((size_t)2 * 1024 * 1024);  // 1MB used + prefetch pad
  float* mq     = (float*)alloc((size_t)N_ * 4);
  float* x      = (float*)alloc((size_t)ROWS * D_ * 4);
  bf16*  xb     = (bf16*) alloc((size_t)ROWS * D_ * 2);
  bf16*  attn_o = (bf16*) alloc((size_t)ROWS * D_ * 2);
  float* tmp    = (float*)alloc((size_t)ROWS * D_ * 4);
  bf16*  qkv    = (bf16*) alloc((size_t)ROWS * 1024 * 2);  // shared: qkv[768] / ffn h1[1024]
  bf16*  h1     = qkv;
  bf16*  Wqkvt  = (bf16*) alloc((size_t)L_ * 768 * 256 * 2);
  bf16*  Wot    = (bf16*) alloc((size_t)L_ * 256 * 256 * 2);
  bf16*  W1t    = (bf16*) alloc((size_t)L_ * 1024 * 256 * 2);
  bf16*  W2t    = (bf16*) alloc((size_t)L_ * 256 * 1024 * 2);
  float* bqkv   = (float*)alloc((size_t)L_ * 768 * 4);

  bias_gemm<<<dim3(32, 32), dim3(16, 16), 0, stream>>>(e2, e1, biasP);
  colmax<<<2, 256, 0, stream>>>(biasP, mq);
  subm<<<256, 256, 0, stream>>>(biasP, mq);
  convT<<<dim3(8, 8, L_),  256, 0, stream>>>(Wq, Wqkvt,          256, 256, 65536, 196608);
  convT<<<dim3(8, 8, L_),  256, 0, stream>>>(Wk, Wqkvt + 65536,  256, 256, 65536, 196608);
  convT<<<dim3(8, 8, L_),  256, 0, stream>>>(Wv, Wqkvt + 131072, 256, 256, 65536, 196608);
  convT<<<dim3(8, 8, L_),  256, 0, stream>>>(Wo, Wot,            256, 256, 65536, 65536);
  convT<<<dim3(32, 8, L_), 256, 0, stream>>>(W1, W1t, 256, 1024, 262144, 262144);
  convT<<<dim3(8, 32, L_), 256, 0, stream>>>(W2, W2t, 1024, 256, 262144, 262144);
  pack_bqkv<<<12, 256, 0, stream>>>(bq, bk, bv, bqkv);
  init_x<<<ROWS * D_ / 1024, 256, 0, stream>>>(src, x, xb);

  for (int l = 0; l < L_; ++l) {
    // QKV: M=16384, N=768, K=256; 128x128, grid 768 = 3/CU
    gemm_bf16k<128, 128, 3, 0, 1, 0><<<768, 256, 0, stream>>>(
        xb, Wqkvt + (size_t)l * 196608, bqkv + l * 768, nullptr, qkv,
        ROWS, 768, 256, 6);
    attn_k<<<1024, 256, 0, stream>>>(qkv, biasP, attn_o);
    // Wo + residual: M=16384, N=256, K=256; 64x128, grid 512 = 4/CU
    gemm_bf16k<64, 128, 4, 0, 0, 1><<<512, 256, 0, stream>>>(
        attn_o, Wot + (size_t)l * 65536, bo + l * 256, x, tmp,
        ROWS, 256, 256, 2);
    ln_kernel<<<ROWS / 4, 256, 0, stream>>>(tmp, g1 + l * 256, be1 + l * 256, x, xb);
    // W1 + ReLU: M=16384, N=1024, K=256; 128x256, grid 512 = 2/CU
    gemm_bf16k<128, 256, 2, 1, 1, 0><<<512, 256, 0, stream>>>(
        xb, W1t + (size_t)l * 262144, b1 + l * 1024, nullptr, h1,
        ROWS, 1024, 256, 4);
    // W2 + residual: M=16384, N=256, K=1024; 64x128, grid 512 = 4/CU
    gemm_bf16k<64, 128, 4, 0, 0, 1><<<512, 256, 0, stream>>>(
        h1, W2t + (size_t)l * 262144, b2 + l * 256, x, tmp,
        ROWS, 256, 1024, 2);
    float* xout = (l == L_ - 1) ? (float*)d_out : x;
    ln_kernel<<<ROWS / 4, 256, 0, stream>>>(tmp, g2 + l * 256, be2 + l * 256, xout, xb);
  }
}

// Round 8
// 487.283 us; speedup vs baseline: 1.2288x; 1.1169x over previous
//
#include <hip/hip_runtime.h>

typedef __bf16 bf16;
typedef __bf16 v8bf __attribute__((ext_vector_type(8)));
typedef float  v4f  __attribute__((ext_vector_type(4)));
typedef float  v16f __attribute__((ext_vector_type(16)));
typedef unsigned short u16;
typedef u16 v8us __attribute__((ext_vector_type(8)));
typedef unsigned int v4u __attribute__((ext_vector_type(4)));

#define L_ 4
#define B_ 32
#define N_ 512
#define D_ 256
#define H_ 8
#define F_ 1024
#define ROWS (B_*N_)               // 16384
#define QHSZ ((size_t)B_*H_*N_*32) // elems per Q/K/V head-major section

__device__ __forceinline__ void gload16(const void* g, void* l) {
  __builtin_amdgcn_global_load_lds((__attribute__((address_space(1))) void*)g,
                                   (__attribute__((address_space(3))) void*)l,
                                   16, 0, 0);
}

__device__ __forceinline__ unsigned pk_bf16(float a, float b) {
  unsigned r;
  asm("v_cvt_pk_bf16_f32 %0, %1, %2" : "=v"(r) : "v"(a), "v"(b));
  return r;
}

// swap: a.hi <-> b.lo
#define PLSWAP(a, b) asm volatile("v_permlane32_swap_b32 %0, %1" : "+v"(a), "+v"(b))

#define EXP2(x) __builtin_amdgcn_exp2f(x)

template <int N> __device__ __forceinline__ void waitvm() {
  if constexpr (N == 0) asm volatile("s_waitcnt vmcnt(0)" ::: "memory");
  else if constexpr (N == 2) asm volatile("s_waitcnt vmcnt(2)" ::: "memory");
  else if constexpr (N == 3) asm volatile("s_waitcnt vmcnt(3)" ::: "memory");
  else if constexpr (N == 4) asm volatile("s_waitcnt vmcnt(4)" ::: "memory");
  else if constexpr (N == 5) asm volatile("s_waitcnt vmcnt(5)" ::: "memory");
  else if constexpr (N == 6) asm volatile("s_waitcnt vmcnt(6)" ::: "memory");
}

// ---------------- biasP (permuted, MFMA C-layout) = (e2 @ e1^T) * log2e ----------------
__global__ __launch_bounds__(256) void bias_gemm(
    const float* __restrict__ e1, const float* __restrict__ e2,
    float* __restrict__ biasP) {
  __shared__ float As[16][16];
  __shared__ float Bs[16][16];
  const int tx = threadIdx.x, ty = threadIdx.y;
  const int r = blockIdx.y * 16 + ty, c = blockIdx.x * 16 + tx;
  float acc = 0.f;
  for (int k0 = 0; k0 < D_; k0 += 16) {
    As[ty][tx] = e1[r * D_ + k0 + tx];
    Bs[ty][tx] = e2[(blockIdx.x * 16 + ty) * D_ + k0 + tx];
    __syncthreads();
#pragma unroll
    for (int kk = 0; kk < 16; ++kk) acc += As[ty][kk] * Bs[tx][kk];
    __syncthreads();
  }
  const int kb = r >> 5, r5 = r & 31;
  const int blk = kb * 8 + (r5 >> 3) * 2 + ((r5 >> 2) & 1);
  biasP[(size_t)(blk * 512 + c) * 4 + (r5 & 3)] = acc * 1.4426950408889634f;
}

// ---------------- mq[q] = max over all k of biasP ----------------
__global__ __launch_bounds__(256) void colmax(
    const float* __restrict__ biasP, float* __restrict__ mq) {
  const int q = blockIdx.x * 256 + threadIdx.x;
  float mx = -1e30f;
  for (int blk = 0; blk < 128; ++blk) {
    const float4 v = *(const float4*)&biasP[(size_t)(blk * 512 + q) * 4];
    mx = fmaxf(mx, fmaxf(fmaxf(v.x, v.y), fmaxf(v.z, v.w)));
  }
  mq[q] = mx;
}

// ---------------- biasP -= mq[q] ----------------
__global__ __launch_bounds__(256) void subm(
    float* __restrict__ biasP, const float* __restrict__ mq) {
  const int i = blockIdx.x * 256 + threadIdx.x;  // 65536 float4
  float4 v = ((float4*)biasP)[i];
  const float m = mq[i & 511];
  v.x -= m; v.y -= m; v.z -= m; v.w -= m;
  ((float4*)biasP)[i] = v;
}

// ---------------- tiled weight transpose + bf16 cast: [K][N] -> [N][K] ----------------
__global__ __launch_bounds__(256) void convT(
    const float* __restrict__ W, bf16* __restrict__ Wt,
    int K, int N, size_t inL, size_t outL) {
  __shared__ float t[32][33];
  const int l = blockIdx.z;
  const int k0 = blockIdx.y * 32, n0 = blockIdx.x * 32;
  const int r = threadIdx.x >> 5, c = threadIdx.x & 31;
#pragma unroll
  for (int i = 0; i < 4; ++i)
    t[r + 8 * i][c] = W[l * inL + (size_t)(k0 + r + 8 * i) * N + n0 + c];
  __syncthreads();
#pragma unroll
  for (int i = 0; i < 4; ++i)
    Wt[l * outL + (size_t)(n0 + r + 8 * i) * K + k0 + c] = (bf16)t[c][r + 8 * i];
}

__global__ __launch_bounds__(256) void pack_bqkv(
    const float* __restrict__ bq, const float* __restrict__ bk,
    const float* __restrict__ bv, float* __restrict__ bqkv) {
  const int i = blockIdx.x * 256 + threadIdx.x;
  if (i < L_ * 768) {
    const int l = i / 768, n = i - l * 768;
    float v = (n < 256) ? bq[l * 256 + n]
            : (n < 512) ? bk[l * 256 + n - 256]
                        : bv[l * 256 + n - 512];
    bqkv[i] = v;
  }
}

__global__ __launch_bounds__(256) void init_x(
    const float* __restrict__ src, bf16* __restrict__ xb) {
  const int i = blockIdx.x * 256 + threadIdx.x;  // float4 index
  float4 v = ((const float4*)src)[i];
  uint2 w;
  w.x = pk_bf16(v.x, v.y);
  w.y = pk_bf16(v.z, v.w);
  ((uint2*)xb)[i] = w;
}

// ---------------- bf16 MFMA GEMM, 2-phase pipelined, XCD-swizzled ----------------
// OUTMODE: 0 = fp32 row-major, 1 = bf16 row-major, 2 = bf16 head-major QKV (N=768)
template <int BM, int BN, int WPC, int RELU, int OUTMODE, int RESID>
__global__ __launch_bounds__(256, WPC) void gemm_bf16k(
    const bf16* __restrict__ A, const bf16* __restrict__ Bt,
    const float* __restrict__ bias, const bf16* __restrict__ resid,
    void* __restrict__ Cout, int M, int N, int K, int nbx) {
  constexpr int MR = BM / 32, NR = BN / 32;
  constexpr int NSLAB = (BM + BN) / 16;
  constexpr int LPW = NSLAB / 4;
  constexpr int BUFE = (BM + BN) * 32;
  __shared__ __align__(16) bf16 lds[3 * BUFE];
  const int tid  = threadIdx.x;
  const int wave = tid >> 6, lane = tid & 63;
  const int l15 = lane & 15, l4 = lane >> 4;
  const int qq = gridDim.x >> 3;
  const int wg = (blockIdx.x & 7) * qq + (blockIdx.x >> 3);
  const int bx = wg % nbx, by = wg / nbx;
  const int bm = by * BM, bn = bx * BN;
  const int wr = (wave >> 1) * (BM / 2), wc = (wave & 1) * (BN / 2);
  const int lrow = lane >> 2;
  const int lk   = (lane & 3) * 8;

  v4f acc[MR][NR];
#pragma unroll
  for (int m = 0; m < MR; ++m)
#pragma unroll
    for (int n = 0; n < NR; ++n) acc[m][n] = (v4f){0.f, 0.f, 0.f, 0.f};

  auto STAGE = [&](int buf, int k0) {
    bf16* dst = &lds[buf * BUFE];
#pragma unroll
    for (int s = wave; s < NSLAB; s += 4) {
      if (s < BM / 16)
        gload16(A + (size_t)(bm + s * 16 + lrow) * K + k0 + lk, dst + s * 512);
      else
        gload16(Bt + (size_t)(bn + (s - BM / 16) * 16 + lrow) * K + k0 + lk, dst + s * 512);
    }
  };

  const int nk = K >> 5;
  STAGE(0, 0);
  STAGE(1, 32);
  waitvm<LPW>();
  __builtin_amdgcn_s_barrier();
  __builtin_amdgcn_sched_barrier(0);

  int cur = 0;
  for (int t = 0; t < nk; ++t) {
    const bool pf = (t + 2 < nk);
    if (pf) STAGE(cur == 0 ? 2 : cur - 1, (t + 2) * 32);
    const bf16* buf = &lds[cur * BUFE];
    v8bf af[MR], bfr[NR];
#pragma unroll
    for (int m = 0; m < MR; ++m)
      af[m] = *(const v8bf*)&buf[(wr + m * 16 + l15) * 32 + l4 * 8];
#pragma unroll
    for (int n = 0; n < NR; ++n)
      bfr[n] = *(const v8bf*)&buf[BM * 32 + (wc + n * 16 + l15) * 32 + l4 * 8];
    __builtin_amdgcn_s_setprio(1);
#pragma unroll
    for (int m = 0; m < MR; ++m)
#pragma unroll
      for (int n = 0; n < NR; ++n)
        acc[m][n] = __builtin_amdgcn_mfma_f32_16x16x32_bf16(af[m], bfr[n], acc[m][n], 0, 0, 0);
    __builtin_amdgcn_s_setprio(0);
    if (pf) waitvm<LPW>();
    else    waitvm<0>();
    __builtin_amdgcn_s_barrier();
    __builtin_amdgcn_sched_barrier(0);
    cur = (cur == 2) ? 0 : cur + 1;
  }

#pragma unroll
  for (int m = 0; m < MR; ++m) {
    const int row0 = bm + wr + m * 16 + l4 * 4;
#pragma unroll
    for (int n = 0; n < NR; ++n) {
      const int col = bn + wc + n * 16 + l15;
      const float bc = bias[col];
      if constexpr (OUTMODE == 2) {
        // head-major QKV: sec (q/k/v), head, d
        const int sec = col >> 8, hh = (col >> 5) & 7, d = col & 31;
        const int bb = row0 >> 9, nr0 = row0 & 511;
        bf16* dst = (bf16*)Cout + (size_t)sec * QHSZ +
                    (((size_t)bb * 8 + hh) * 512 + nr0) * 32 + d;
#pragma unroll
        for (int i = 0; i < 4; ++i)
          dst[i * 32] = (bf16)(acc[m][n][i] + bc);
      } else {
#pragma unroll
        for (int i = 0; i < 4; ++i) {
          const size_t idx = (size_t)(row0 + i) * N + col;
          float v = acc[m][n][i] + bc;
          if (RESID) v += (float)resid[idx];
          if (RELU) v = fmaxf(v, 0.f);
          if (OUTMODE == 1) ((bf16*)Cout)[idx] = (bf16)v;
          else              ((float*)Cout)[idx] = v;
        }
      }
    }
  }
}

// ---------------- fused flash attention, head-major QKV, fixed normalizer ----------------
#define VTS 520
__global__ __launch_bounds__(256, 3) void attn_k(
    const bf16* __restrict__ qkvh, const float* __restrict__ biasP,
    bf16* __restrict__ outp) {
  __shared__ u16 Vt[32 * VTS];   // V^T: [d][kc]
  const int tid = threadIdx.x;
  const int wave = tid >> 6, lane = tid & 63;
  const int l31 = lane & 31, hi = lane >> 5;
  const int fid = blockIdx.x;
  const int xcd = fid & 7, idx = fid >> 3;
  const int b = (xcd << 2) | (idx >> 5);
  const int h = (idx & 31) >> 2;
  const int qblk = idx & 3;
  const u16* Qh = (const u16*)qkvh + (((size_t)b * 8 + h) * 512) * 32;
  const u16* Kh = Qh + QHSZ;
  const u16* Vh = Qh + 2 * QHSZ;
  const int qb = qblk * 128 + wave * 32;

  // ---- stage V^T (once per block): thread t packs rows 2t,2t+1 (contiguous stream) ----
  {
    const u16* p0 = Vh + (size_t)(2 * tid) * 32;
    const u16* p1 = p0 + 32;
#pragma unroll
    for (int d0 = 0; d0 < 32; d0 += 8) {
      v8us a = *(const v8us*)(p0 + d0);
      v8us c = *(const v8us*)(p1 + d0);
#pragma unroll
      for (int j = 0; j < 8; ++j) {
        unsigned u = (unsigned)a[j] | ((unsigned)c[j] << 16);
        *(unsigned*)&Vt[(d0 + j) * VTS + tid * 2] = u;
      }
    }
  }
  __syncthreads();

  // ---- Q fragments (B operand), held all chunks ----
  const u16* qrow = Qh + (size_t)(qb + l31) * 32;
  const v8bf qf0 = *(const v8bf*)(qrow + hi * 8);
  const v8bf qf1 = *(const v8bf*)(qrow + 16 + hi * 8);
  const float* bpl = biasP + ((size_t)(hi * 512 + qb + l31)) * 4;

  const float SC2 = 0.17677669529663688f * 1.4426950408889634f;
  float lsum = 0.f;
  v16f accO = {0.f,0.f,0.f,0.f,0.f,0.f,0.f,0.f,0.f,0.f,0.f,0.f,0.f,0.f,0.f,0.f};

  // chunk-0 operands
  v8bf ka0 = *(const v8bf*)(Kh + (size_t)l31 * 32 + hi * 8);
  v8bf ka1 = *(const v8bf*)(Kh + (size_t)l31 * 32 + 16 + hi * 8);
  v4f bb[4];
#pragma unroll
  for (int g = 0; g < 4; ++g) bb[g] = *(const v4f*)(bpl + (size_t)(g * 2) * 2048);

  v16f stC = {0.f,0.f,0.f,0.f,0.f,0.f,0.f,0.f,0.f,0.f,0.f,0.f,0.f,0.f,0.f,0.f};
  stC = __builtin_amdgcn_mfma_f32_32x32x16_bf16(ka0, qf0, stC, 0, 0, 0);
  stC = __builtin_amdgcn_mfma_f32_32x32x16_bf16(ka1, qf1, stC, 0, 0, 0);
  {
    const u16* kn = Kh + (size_t)(32 + l31) * 32;
    ka0 = *(const v8bf*)(kn + hi * 8);
    ka1 = *(const v8bf*)(kn + 16 + hi * 8);
  }

  for (int kb = 0; kb < 16; ++kb) {
    const int kbase = kb * 32;
    // QK^T(kb+1) early: matrix pipe runs under softmax VALU of chunk kb
    v16f stN = {0.f,0.f,0.f,0.f,0.f,0.f,0.f,0.f,0.f,0.f,0.f,0.f,0.f,0.f,0.f,0.f};
    __builtin_amdgcn_s_setprio(1);
    stN = __builtin_amdgcn_mfma_f32_32x32x16_bf16(ka0, qf0, stN, 0, 0, 0);
    stN = __builtin_amdgcn_mfma_f32_32x32x16_bf16(ka1, qf1, stN, 0, 0, 0);
    __builtin_amdgcn_s_setprio(0);

    // prefetch K(kb+2) and bias(kb+1)  (unconditional; reads spill into V section = valid)
    const u16* kn = Kh + (size_t)(kbase + 64 + l31) * 32;
    const v8bf kn0 = *(const v8bf*)(kn + hi * 8);
    const v8bf kn1 = *(const v8bf*)(kn + 16 + hi * 8);
    v4f bn[4];
#pragma unroll
    for (int g = 0; g < 4; ++g)
      bn[g] = *(const v4f*)(bpl + (size_t)((kb + 1) * 8 + g * 2) * 2048);

    float p[16];
#pragma unroll
    for (int r = 0; r < 16; ++r)
      p[r] = EXP2(stC[r] * SC2 + bb[r >> 2][r & 3]);

    float s8[8], s4[4];
#pragma unroll
    for (int r = 0; r < 8; ++r) s8[r] = p[r] + p[r + 8];
#pragma unroll
    for (int r = 0; r < 4; ++r) s4[r] = s8[r] + s8[r + 4];
    lsum += (s4[0] + s4[2]) + (s4[1] + s4[3]);

    unsigned u[8];
#pragma unroll
    for (int t = 0; t < 8; ++t) u[t] = pk_bf16(p[2 * t], p[2 * t + 1]);
    PLSWAP(u[0], u[2]);
    PLSWAP(u[1], u[3]);
    PLSWAP(u[4], u[6]);
    PLSWAP(u[5], u[7]);
    union { v4u u; v8bf h; } cv0, cv1;
    cv0.u = (v4u){u[0], u[1], u[2], u[3]};
    cv1.u = (v4u){u[4], u[5], u[6], u[7]};

    const v8bf va0 = *(const v8bf*)&Vt[l31 * VTS + kbase + hi * 8];
    const v8bf va1 = *(const v8bf*)&Vt[l31 * VTS + kbase + 16 + hi * 8];
    __builtin_amdgcn_s_setprio(1);
    accO = __builtin_amdgcn_mfma_f32_32x32x16_bf16(va0, cv0.h, accO, 0, 0, 0);
    accO = __builtin_amdgcn_mfma_f32_32x32x16_bf16(va1, cv1.h, accO, 0, 0, 0);
    __builtin_amdgcn_s_setprio(0);

    stC = stN;
    ka0 = kn0; ka1 = kn1;
#pragma unroll
    for (int g = 0; g < 4; ++g) bb[g] = bn[g];
  }

  lsum += __shfl_xor(lsum, 32);

  const float inv = 1.0f / lsum;
  u16* orow = (u16*)outp + (size_t)(b * N_ + qb + l31) * D_ + h * 32 + 4 * hi;
#pragma unroll
  for (int g = 0; g < 4; ++g) {
    uint2 w;
    w.x = pk_bf16(accO[4 * g] * inv, accO[4 * g + 1] * inv);
    w.y = pk_bf16(accO[4 * g + 2] * inv, accO[4 * g + 3] * inv);
    *(uint2*)(orow + 8 * g) = w;
  }
}

// ---------------- LayerNorm: tmp fp32 in -> xb bf16 out (WF32: fp32 out for d_out) ----------------
template <int WF32>
__global__ __launch_bounds__(256) void ln_kernel(
    const float* __restrict__ xin,
    const float* __restrict__ g, const float* __restrict__ b,
    float* __restrict__ xout_f32, bf16* __restrict__ xbout) {
  const int wv = threadIdx.x >> 6, ln = threadIdx.x & 63;
  const size_t row = blockIdx.x * 4 + wv;
  const size_t o4 = row * D_ + ln * 4;
  const float4 v = *(const float4*)&xin[o4];
  float s  = (v.x + v.y) + (v.z + v.w);
  float ss = (v.x * v.x + v.y * v.y) + (v.z * v.z + v.w * v.w);
#pragma unroll
  for (int off = 1; off < 64; off <<= 1) {
    s  += __shfl_xor(s, off);
    ss += __shfl_xor(ss, off);
  }
  const float mu = s * (1.f / D_);
  const float var = ss * (1.f / D_) - mu * mu;
  const float rs = rsqrtf(var + 1e-5f);
  const float4 gg = *(const float4*)&g[ln * 4];
  const float4 bb = *(const float4*)&b[ln * 4];
  float4 o;
  o.x = (v.x - mu) * rs * gg.x + bb.x;
  o.y = (v.y - mu) * rs * gg.y + bb.y;
  o.z = (v.z - mu) * rs * gg.z + bb.z;
  o.w = (v.w - mu) * rs * gg.w + bb.w;
  if constexpr (WF32) {
    *(float4*)&xout_f32[o4] = o;
  } else {
    uint2 w;
    w.x = pk_bf16(o.x, o.y);
    w.y = pk_bf16(o.z, o.w);
    *(uint2*)&xbout[o4] = w;
  }
}

extern "C" void kernel_launch(void* const* d_in, const int* in_sizes, int n_in,
                              void* d_out, int out_size, void* d_ws, size_t ws_size,
                              hipStream_t stream) {
  const float* src = (const float*)d_in[0];
  const float* e1  = (const float*)d_in[1];
  const float* e2  = (const float*)d_in[2];
  const float* Wq  = (const float*)d_in[3];
  const float* bq  = (const float*)d_in[4];
  const float* Wk  = (const float*)d_in[5];
  const float* bk  = (const float*)d_in[6];
  const float* Wv  = (const float*)d_in[7];
  const float* bv  = (const float*)d_in[8];
  const float* Wo  = (const float*)d_in[9];
  const float* bo  = (const float*)d_in[10];
  const float* W1  = (const float*)d_in[11];
  const float* b1  = (const float*)d_in[12];
  const float* W2  = (const float*)d_in[13];
  const float* b2  = (const float*)d_in[14];
  const float* g1  = (const float*)d_in[15];
  const float* be1 = (const float*)d_in[16];
  const float* g2  = (const float*)d_in[17];
  const float* be2 = (const float*)d_in[18];

  char* ws = (char*)d_ws;
  size_t off = 0;
  auto alloc = [&](size_t bytes) {
    void* p = ws + off;
    off += (bytes + 255) & ~(size_t)255;
    return p;
  };
  float* biasP  = (float*)alloc((size_t)2 * 1024 * 1024);  // 1.1MB used + prefetch pad
  float* mq     = (float*)alloc((size_t)N_ * 4);
  bf16*  xb     = (bf16*) alloc((size_t)ROWS * D_ * 2);
  bf16*  attn_o = (bf16*) alloc((size_t)ROWS * D_ * 2);
  float* tmp    = (float*)alloc((size_t)ROWS * D_ * 4);
  bf16*  qkvh   = (bf16*) alloc((size_t)ROWS * 1024 * 2 + 65536);  // shared: head-major qkv (25.2MB) / ffn h1 (33.5MB)
  bf16*  h1     = qkvh;
  bf16*  Wqkvt  = (bf16*) alloc((size_t)L_ * 768 * 256 * 2);
  bf16*  Wot    = (bf16*) alloc((size_t)L_ * 256 * 256 * 2);
  bf16*  W1t    = (bf16*) alloc((size_t)L_ * 1024 * 256 * 2);
  bf16*  W2t    = (bf16*) alloc((size_t)L_ * 256 * 1024 * 2);
  float* bqkv   = (float*)alloc((size_t)L_ * 768 * 4);

  bias_gemm<<<dim3(32, 32), dim3(16, 16), 0, stream>>>(e2, e1, biasP);
  colmax<<<2, 256, 0, stream>>>(biasP, mq);
  subm<<<256, 256, 0, stream>>>(biasP, mq);
  convT<<<dim3(8, 8, L_),  256, 0, stream>>>(Wq, Wqkvt,          256, 256, 65536, 196608);
  convT<<<dim3(8, 8, L_),  256, 0, stream>>>(Wk, Wqkvt + 65536,  256, 256, 65536, 196608);
  convT<<<dim3(8, 8, L_),  256, 0, stream>>>(Wv, Wqkvt + 131072, 256, 256, 65536, 196608);
  convT<<<dim3(8, 8, L_),  256, 0, stream>>>(Wo, Wot,            256, 256, 65536, 65536);
  convT<<<dim3(32, 8, L_), 256, 0, stream>>>(W1, W1t, 256, 1024, 262144, 262144);
  convT<<<dim3(8, 32, L_), 256, 0, stream>>>(W2, W2t, 1024, 256, 262144, 262144);
  pack_bqkv<<<12, 256, 0, stream>>>(bq, bk, bv, bqkv);
  init_x<<<ROWS * D_ / 1024, 256, 0, stream>>>(src, xb);

  for (int l = 0; l < L_; ++l) {
    // QKV: M=16384, N=768, K=256; 128x128, head-major output
    gemm_bf16k<128, 128, 3, 0, 2, 0><<<768, 256, 0, stream>>>(
        xb, Wqkvt + (size_t)l * 196608, bqkv + l * 768, nullptr, qkvh,
        ROWS, 768, 256, 6);
    attn_k<<<1024, 256, 0, stream>>>(qkvh, biasP, attn_o);
    // Wo + residual(xb): 64x128, fp32 tmp out
    gemm_bf16k<64, 128, 4, 0, 0, 1><<<512, 256, 0, stream>>>(
        attn_o, Wot + (size_t)l * 65536, bo + l * 256, xb, tmp,
        ROWS, 256, 256, 2);
    ln_kernel<0><<<ROWS / 4, 256, 0, stream>>>(tmp, g1 + l * 256, be1 + l * 256, nullptr, xb);
    // W1 + ReLU: 128x256, bf16 out
    gemm_bf16k<128, 256, 2, 1, 1, 0><<<512, 256, 0, stream>>>(
        xb, W1t + (size_t)l * 262144, b1 + l * 1024, nullptr, h1,
        ROWS, 1024, 256, 4);
    // W2 + residual(xb): 64x128, fp32 tmp out
    gemm_bf16k<64, 128, 4, 0, 0, 1><<<512, 256, 0, stream>>>(
        h1, W2t + (size_t)l * 262144, b2 + l * 256, xb, tmp,
        ROWS, 256, 1024, 2);
    if (l == L_ - 1)
      ln_kernel<1><<<ROWS / 4, 256, 0, stream>>>(tmp, g2 + l * 256, be2 + l * 256, (float*)d_out, nullptr);
    else
      ln_kernel<0><<<ROWS / 4, 256, 0, stream>>>(tmp, g2 + l * 256, be2 + l * 256, nullptr, xb);
  }
}